// Round 6
// baseline (1795.358 us; speedup 1.0000x reference)
//
#include <hip/hip_runtime.h>
#include <cstdint>
#include <cstddef>

typedef _Float16 half8 __attribute__((ext_vector_type(8)));
typedef float f32x4 __attribute__((ext_vector_type(4)));
typedef unsigned short ushort_t;

// ---------- constants ----------
#define BB 8
#define NN 4096
#define CIN 64
#define SS 1024
#define KK 32
#define O1 128
#define O2 128
#define O3 256
#define C0 67          // 3 + CIN
#define P0 104         // LDS pitch for feat0 (odd multiple of 8 halves = 16B)
#define P1 136         // LDS pitch for activations (odd multiple of 8 halves)
#define MTOT (BB*SS*KK)   // 262144 rows
#define NBLK 4096         // fused grid: B * S/2

// ---------- helpers ----------
__device__ __forceinline__ ushort_t f2h(float v) {
  union { _Float16 h; ushort_t u; } cv;
  cv.h = (_Float16)v;
  return cv.u;
}
__device__ __forceinline__ half8 ldv(const ushort_t* p) {
  return *(const half8*)p;
}
__device__ __forceinline__ f32x4 MF(half8 a, half8 b, f32x4 c) {
  return __builtin_amdgcn_mfma_f32_16x16x32_f16(a, b, c, 0, 0, 0);
}

// ---- DPP-only 64-lane (value, idx) reduce; result lands in LANE 63.
// MAXM=true: argmax (ties -> smaller idx). MAXM=false: argmin (ties -> smaller idx).
template<bool MAXM>
__device__ __forceinline__ void wave_red_dpp(float& d, int& i) {
#define RED_TAKE(d2, i2) \
  { bool take = MAXM ? ((d2) > d || ((d2) == d && (i2) < i)) \
                     : ((d2) < d || ((d2) == d && (i2) < i)); \
    if (take) { d = (d2); i = (i2); } }
#define RED_DPP(CTRL) \
  { float d2_ = __int_as_float(__builtin_amdgcn_update_dpp(0, __float_as_int(d), CTRL, 0xf, 0xf, true)); \
    int   i2_ = __builtin_amdgcn_update_dpp(0, i, CTRL, 0xf, 0xf, true); \
    RED_TAKE(d2_, i2_) }
  RED_DPP(0x128)   // row_ror:8
  RED_DPP(0x124)   // row_ror:4
  RED_DPP(0x122)   // row_ror:2
  RED_DPP(0x121)   // row_ror:1
  RED_DPP(0x142)   // row_bcast:15
  RED_DPP(0x143)   // row_bcast:31
#undef RED_DPP
#undef RED_TAKE
}

// ---------- 1. FPS: one block (512 thr, 8 waves = 2/SIMD) per batch ----------
__global__ __launch_bounds__(512, 1) void fps_kernel(const float* __restrict__ xyz,
                                                     float* __restrict__ newxyz) {
  int b = blockIdx.x, t = threadIdx.x;
  __shared__ float sxyz[NN*3];
  __shared__ float snew[SS*3];                    // centroid buffer
  __shared__ __align__(16) float wpair[2][8][2];  // [parity][wave][{dist, idx-bits}]
  {
    const float4* src = (const float4*)(xyz + (size_t)b * (NN*3));
    float4* dst = (float4*)sxyz;
    for (int i = t; i < NN*3/4; i += 512) dst[i] = src[i];
  }
  __syncthreads();
  float px[8], py[8], pz[8], dist[8];
#pragma unroll
  for (int j = 0; j < 8; ++j) {
    int n = t + 512*j;
    px[j] = sxyz[n*3+0]; py[j] = sxyz[n*3+1]; pz[j] = sxyz[n*3+2];
    dist[j] = 1e10f;
  }
  float cx = sxyz[0], cy = sxyz[1], cz = sxyz[2];
  for (int s = 0; s < SS; ++s) {
    if (t == 0) {
      snew[s*3+0] = cx; snew[s*3+1] = cy; snew[s*3+2] = cz;
    }
    // distance + 4 independent argmax chains (dep depth 2)
    float bd0 = -1.f, bd1 = -1.f, bd2 = -1.f, bd3 = -1.f;
    int   bi0 = 0, bi1 = 0, bi2 = 0, bi3 = 0;
#pragma unroll
    for (int j = 0; j < 8; ++j) {
      // exact np order: ((dx*dx + dy*dy) + dz*dz), no FMA contraction
      float dx = __fadd_rn(px[j], -cx);
      float dy = __fadd_rn(py[j], -cy);
      float dz = __fadd_rn(pz[j], -cz);
      float d = __fadd_rn(__fadd_rn(__fmul_rn(dx,dx), __fmul_rn(dy,dy)), __fmul_rn(dz,dz));
      float nd = fminf(dist[j], d);
      dist[j] = nd;
      int idx = t + 512*j;
      // within a chain j increases -> strict > keeps first (smallest) index on tie
      if ((j & 3) == 0) { if (nd > bd0) { bd0 = nd; bi0 = idx; } }
      if ((j & 3) == 1) { if (nd > bd1) { bd1 = nd; bi1 = idx; } }
      if ((j & 3) == 2) { if (nd > bd2) { bd2 = nd; bi2 = idx; } }
      if ((j & 3) == 3) { if (nd > bd3) { bd3 = nd; bi3 = idx; } }
    }
    // combine chains, tie-break by smaller index (np.argmax = first max)
    float bd = bd0; int bi = bi0;
    if (bd1 > bd || (bd1 == bd && bi1 < bi)) { bd = bd1; bi = bi1; }
    if (bd2 > bd || (bd2 == bd && bi2 < bi)) { bd = bd2; bi = bi2; }
    if (bd3 > bd || (bd3 == bd && bi3 < bi)) { bd = bd3; bi = bi3; }

    wave_red_dpp<true>(bd, bi);     // result in lane 63

    int p = s & 1;
    if ((t & 63) == 63) {
      wpair[p][t>>6][0] = bd;
      ((int*)&wpair[p][t>>6][0])[1] = bi;
    }
    __syncthreads();
    // packed read of all 8 (dist,idx) partials: 4x float4, pipelined
    float4 q0 = *(const float4*)&wpair[p][0][0];
    float4 q1 = *(const float4*)&wpair[p][2][0];
    float4 q2 = *(const float4*)&wpair[p][4][0];
    float4 q3 = *(const float4*)&wpair[p][6][0];
    float fd = q0.x; int fi = __float_as_int(q0.y);
#define CMB(dv, iv) { float od = (dv); int oi = __float_as_int(iv); \
      if (od > fd || (od == fd && oi < fi)) { fd = od; fi = oi; } }
    CMB(q0.z, q0.w) CMB(q1.x, q1.y) CMB(q1.z, q1.w)
    CMB(q2.x, q2.y) CMB(q2.z, q2.w) CMB(q3.x, q3.y) CMB(q3.z, q3.w)
#undef CMB
    cx = sxyz[fi*3+0]; cy = sxyz[fi*3+1]; cz = sxyz[fi*3+2];
  }
  __syncthreads();
  { // coalesced write-out of all centroids
    float4* dst = (float4*)(newxyz + (size_t)b * (SS*3));
    const float4* src = (const float4*)snew;
    for (int i = t; i < SS*3/4; i += 512) dst[i] = src[i];
  }
}

// ---------- 2. KNN: one block per query, extract-min 32x ----------
__global__ __launch_bounds__(256) void knn_kernel(const float* __restrict__ xyz,
                                                  const float* __restrict__ newxyz,
                                                  int* __restrict__ nn) {
  int blk = blockIdx.x;           // b*1024 + s
  int b = blk >> 10;
  int t = threadIdx.x;
  __shared__ float ld[2][4];
  __shared__ int   li[2][4];
  float qx = newxyz[(size_t)blk*3+0];
  float qy = newxyz[(size_t)blk*3+1];
  float qz = newxyz[(size_t)blk*3+2];
  float cs = __fadd_rn(__fadd_rn(__fmul_rn(qx,qx), __fmul_rn(qy,qy)), __fmul_rn(qz,qz));
  const float* base = xyz + (size_t)b * (NN*3);
  float d[16];
#pragma unroll
  for (int j = 0; j < 16; ++j) {
    int n = t + 256*j;
    float px = base[n*3+0], py = base[n*3+1], pz = base[n*3+2];
    float xs  = __fadd_rn(__fadd_rn(__fmul_rn(px,px), __fmul_rn(py,py)), __fmul_rn(pz,pz));
    float dot = __fadd_rn(__fadd_rn(__fmul_rn(qx,px), __fmul_rn(qy,py)), __fmul_rn(qz,pz));
    // reference: (cs - 2*dot) + xs
    d[j] = __fadd_rn(__fadd_rn(cs, -__fmul_rn(2.f, dot)), xs);
  }
  int* myout = nn + (size_t)blk * KK;
  for (int it = 0; it < KK; ++it) {
    float bd = 3.0e38f; int bi = 0x7fffffff;
#pragma unroll
    for (int j = 0; j < 16; ++j) {
      if (d[j] < bd) { bd = d[j]; bi = t + 256*j; }   // strict < keeps smaller idx
    }
    wave_red_dpp<false>(bd, bi);    // result in lane 63
    int p = it & 1;
    if ((t & 63) == 63) { ld[p][t>>6] = bd; li[p][t>>6] = bi; }
    __syncthreads();
    float fd = ld[p][0]; int fi = li[p][0];
#pragma unroll
    for (int w2 = 1; w2 < 4; ++w2) {
      float od = ld[p][w2]; int oi = li[p][w2];
      if (od < fd || (od == fd && oi < fi)) { fd = od; fi = oi; }
    }
    if ((fi & 255) == t) {
      int jj = fi >> 8;
#pragma unroll
      for (int j = 0; j < 16; ++j) if (j == jj) d[j] = 3.0e38f;
    }
    if (t == 0) myout[it] = fi;
  }
}

// ---------- 3. weights fp32 -> fp16, zero-padded ----------
__global__ void prep_kernel(const float* __restrict__ W0, const float* __restrict__ W1,
                            const float* __restrict__ W2,
                            ushort_t* __restrict__ wb1, ushort_t* __restrict__ wb2,
                            ushort_t* __restrict__ wb3) {
  int i = blockIdx.x*256 + threadIdx.x;
  int stride = gridDim.x*256;
  const int n1 = O1*96, n2 = O2*128, n3 = O3*128;
  for (; i < n1+n2+n3; i += stride) {
    if (i < n1) {
      int o = i / 96, k = i - o*96;
      wb1[i] = (k < C0) ? f2h(W0[o*C0 + k]) : (ushort_t)0;
    } else if (i < n1+n2) {
      int j = i - n1;
      wb2[j] = f2h(W1[j]);
    } else {
      int j = i - n1 - n2;
      wb3[j] = f2h(W2[j]);
    }
  }
}

// ---------- shared epilogue helper (fallback path) ----------
template<int NT>
__device__ __forceinline__ void stats_and_store(
    const f32x4* acc, const float* __restrict__ bias,
    float (*sred)[256][2],
    int w, int lr, int lg, int t, int blk,
    float* __restrict__ psum, float* __restrict__ psq)
{
#pragma unroll
  for (int n = 0; n < NT; ++n) {
    int c = n*16 + lr;
    float bi = bias[c];
    float x0 = acc[n][0]+bi, x1 = acc[n][1]+bi, x2 = acc[n][2]+bi, x3 = acc[n][3]+bi;
    float s4 = (x0+x1)+(x2+x3);
    float q4 = (x0*x0+x1*x1)+(x2*x2+x3*x3);
    s4 += __shfl_xor(s4, 16); s4 += __shfl_xor(s4, 32);
    q4 += __shfl_xor(q4, 16); q4 += __shfl_xor(q4, 32);
    if (lg == 0) { sred[w][c][0] = s4; sred[w][c][1] = q4; }
  }
  __syncthreads();
  if (t < NT*16) {
    float ps = (sred[0][t][0]+sred[1][t][0])+(sred[2][t][0]+sred[3][t][0]);
    float pq = (sred[0][t][1]+sred[1][t][1])+(sred[2][t][1]+sred[3][t][1]);
    psum[(size_t)t*NBLK + blk] = ps;
    psq [(size_t)t*NBLK + blk] = pq;
  }
}

// ---------- feat0 staging (shared by conv1 + fallback) ----------
__device__ __forceinline__ void stage_feat0(
    const float* __restrict__ xyz, const float* __restrict__ points,
    const float* __restrict__ newxyz, const int* __restrict__ nn,
    ushort_t* sF, int t, int b, int pr)
{
  int r = t >> 2, q = t & 3;
  int gi = r >> 5, j = r & 31;
  int bs = (b << 10) + (pr*2 + gi);
  int idx = nn[(size_t)bs*KK + j];
  const float* prow = points + ((size_t)(b*NN + idx))*CIN;
  const float* pxyz = xyz    + ((size_t)(b*NN + idx))*3;
  const float* ctr  = newxyz + (size_t)bs*3;
  ushort_t* dst = &sF[r*P0];
  if (q < 3) dst[q] = f2h(pxyz[q] - ctr[q]);
#pragma unroll
  for (int ii = 0; ii < 4; ++ii) {
    float4 v = *(const float4*)&prow[q*4 + ii*16];
    int c = 3 + q*4 + ii*16;
    dst[c+0] = f2h(v.x); dst[c+1] = f2h(v.y); dst[c+2] = f2h(v.z); dst[c+3] = f2h(v.w);
  }
  for (int c = C0 + q; c < P0; c += 4) dst[c] = 0;
}

// ---------- 4a. conv1 (materialized): feat0 -> conv1 -> z + stats1 ----------
__global__ __launch_bounds__(256) void conv1_kernel(
    const float* __restrict__ xyz, const float* __restrict__ points,
    const float* __restrict__ newxyz, const int* __restrict__ nn,
    const ushort_t* __restrict__ wb1, const float* __restrict__ bias1,
    ushort_t* __restrict__ z, float* __restrict__ psum, float* __restrict__ psq)
{
  __shared__ __align__(16) ushort_t sF[64*P0];
  __shared__ __align__(16) ushort_t s1[64*P1];
  __shared__ float sred[4][O1][2];
  int t = threadIdx.x, blk = blockIdx.x;
  int b = blk >> 9, pr = blk & 511;

  stage_feat0(xyz, points, newxyz, nn, sF, t, b, pr);
  __syncthreads();

  int w = t >> 6, l = t & 63;
  int lr = l & 15, lg = l >> 4;
  int ko = lg * 8;
  int arow = w*16 + lr;

  half8 a0 = ldv(&sF[arow*P0 +  0 + ko]);
  half8 a1 = ldv(&sF[arow*P0 + 32 + ko]);
  half8 a2 = ldv(&sF[arow*P0 + 64 + ko]);
  f32x4 acc1[8];
#pragma unroll
  for (int n = 0; n < 8; ++n) {
    const ushort_t* wrow = wb1 + (size_t)(n*16 + lr)*96 + ko;
    f32x4 c = {0.f,0.f,0.f,0.f};
    c = MF(a0, ldv(wrow +  0), c);
    c = MF(a1, ldv(wrow + 32), c);
    c = MF(a2, ldv(wrow + 64), c);
    acc1[n] = c;
  }

  // epilogue: raw acc -> s1 (for coalesced z store), stats on acc+bias
#pragma unroll
  for (int n = 0; n < 8; ++n) {
    int c = n*16 + lr;
#pragma unroll
    for (int rr = 0; rr < 4; ++rr)
      s1[(w*16 + lg*4 + rr)*P1 + c] = f2h(acc1[n][rr]);
    float bi = bias1[c];
    float x0 = acc1[n][0]+bi, x1 = acc1[n][1]+bi, x2 = acc1[n][2]+bi, x3 = acc1[n][3]+bi;
    float s4 = (x0+x1)+(x2+x3);
    float q4 = (x0*x0+x1*x1)+(x2*x2+x3*x3);
    s4 += __shfl_xor(s4, 16); s4 += __shfl_xor(s4, 32);
    q4 += __shfl_xor(q4, 16); q4 += __shfl_xor(q4, 32);
    if (lg == 0) { sred[w][c][0] = s4; sred[w][c][1] = q4; }
  }
  __syncthreads();
  { // coalesced z store: 64 rows x 128 halves
    size_t chunk = (size_t)blk * (64*128);
#pragma unroll
    for (int i = 0; i < 4; ++i) {
      int off = t*8 + i*2048;
      *(half8*)&z[chunk + off] = ldv(&s1[(off>>7)*P1 + (off&127)]);
    }
  }
  if (t < O1) {
    float ps = (sred[0][t][0]+sred[1][t][0])+(sred[2][t][0]+sred[3][t][0]);
    float pq = (sred[0][t][1]+sred[1][t][1])+(sred[2][t][1]+sred[3][t][1]);
    psum[(size_t)t*NBLK + blk] = ps;
    psq [(size_t)t*NBLK + blk] = pq;
  }
}

// ---------- 4b. conv2 (materialized): z -> affine1+relu -> conv2 -> z + stats2 ----------
__global__ __launch_bounds__(256) void conv2_kernel(
    ushort_t* __restrict__ z, const ushort_t* __restrict__ wb2,
    const float* __restrict__ bias2,
    const float* __restrict__ aa1, const float* __restrict__ bb1,
    float* __restrict__ psum, float* __restrict__ psq)
{
  __shared__ __align__(16) ushort_t s1[64*P1];
  __shared__ float sred[4][O2][2];
  int t = threadIdx.x, blk = blockIdx.x;
  size_t chunk = (size_t)blk * (64*128);

  int c0 = (t*8) & 127;
  float av[8], bv[8];
  {
    float4 alo = *(const float4*)&aa1[c0], ahi = *(const float4*)&aa1[c0+4];
    float4 blo = *(const float4*)&bb1[c0], bhi = *(const float4*)&bb1[c0+4];
    av[0]=alo.x; av[1]=alo.y; av[2]=alo.z; av[3]=alo.w;
    av[4]=ahi.x; av[5]=ahi.y; av[6]=ahi.z; av[7]=ahi.w;
    bv[0]=blo.x; bv[1]=blo.y; bv[2]=blo.z; bv[3]=blo.w;
    bv[4]=bhi.x; bv[5]=bhi.y; bv[6]=bhi.z; bv[7]=bhi.w;
  }
#pragma unroll
  for (int i = 0; i < 4; ++i) {
    int off = t*8 + i*2048;
    half8 v = ldv(&z[chunk + off]);
    half8 y;
#pragma unroll
    for (int jj = 0; jj < 8; ++jj)
      y[jj] = (_Float16)fmaxf(av[jj]*(float)v[jj] + bv[jj], 0.f);
    *(half8*)&s1[(off>>7)*P1 + c0] = y;
  }
  __syncthreads();

  int w = t >> 6, l = t & 63;
  int lr = l & 15, lg = l >> 4;
  int ko = lg * 8;
  int arow = w*16 + lr;

  half8 f0 = ldv(&s1[arow*P1 +  0 + ko]);
  half8 f1 = ldv(&s1[arow*P1 + 32 + ko]);
  half8 f2 = ldv(&s1[arow*P1 + 64 + ko]);
  half8 f3 = ldv(&s1[arow*P1 + 96 + ko]);
  f32x4 acc2[8];
#pragma unroll
  for (int n = 0; n < 8; ++n) {
    const ushort_t* wrow = wb2 + (size_t)(n*16 + lr)*128 + ko;
    f32x4 c = {0.f,0.f,0.f,0.f};
    c = MF(f0, ldv(wrow +  0), c);
    c = MF(f1, ldv(wrow + 32), c);
    c = MF(f2, ldv(wrow + 64), c);
    c = MF(f3, ldv(wrow + 96), c);
    acc2[n] = c;
  }
  __syncthreads();   // all s1 frag reads done before overwrite

#pragma unroll
  for (int n = 0; n < 8; ++n) {
    int c = n*16 + lr;
#pragma unroll
    for (int rr = 0; rr < 4; ++rr)
      s1[(w*16 + lg*4 + rr)*P1 + c] = f2h(acc2[n][rr]);
    float bi = bias2[c];
    float x0 = acc2[n][0]+bi, x1 = acc2[n][1]+bi, x2 = acc2[n][2]+bi, x3 = acc2[n][3]+bi;
    float s4 = (x0+x1)+(x2+x3);
    float q4 = (x0*x0+x1*x1)+(x2*x2+x3*x3);
    s4 += __shfl_xor(s4, 16); s4 += __shfl_xor(s4, 32);
    q4 += __shfl_xor(q4, 16); q4 += __shfl_xor(q4, 32);
    if (lg == 0) { sred[w][c][0] = s4; sred[w][c][1] = q4; }
  }
  __syncthreads();
#pragma unroll
  for (int i = 0; i < 4; ++i) {
    int off = t*8 + i*2048;
    *(half8*)&z[chunk + off] = ldv(&s1[(off>>7)*P1 + (off&127)]);
  }
  if (t < O2) {
    float ps = (sred[0][t][0]+sred[1][t][0])+(sred[2][t][0]+sred[3][t][0]);
    float pq = (sred[0][t][1]+sred[1][t][1])+(sred[2][t][1]+sred[3][t][1]);
    psum[(size_t)t*NBLK + blk] = ps;
    psq [(size_t)t*NBLK + blk] = pq;
  }
}

// ---------- 4c. conv3 (materialized): z -> affine2+relu -> conv3 -> stats3 + max/min ----------
__global__ __launch_bounds__(256) void conv3_kernel(
    const ushort_t* __restrict__ z, const ushort_t* __restrict__ wb3,
    const float* __restrict__ bias3,
    const float* __restrict__ aa2, const float* __restrict__ bb2,
    float* __restrict__ psum, float* __restrict__ psq,
    float* __restrict__ maxb, float* __restrict__ minb)
{
  __shared__ __align__(16) ushort_t s2[64*P1];
  __shared__ float sred[4][O3][2];
  __shared__ float smm[4][O3][2];
  int t = threadIdx.x, blk = blockIdx.x;
  int b = blk >> 9, pr = blk & 511;
  size_t chunk = (size_t)blk * (64*128);

  int c0 = (t*8) & 127;
  float av[8], bv[8];
  {
    float4 alo = *(const float4*)&aa2[c0], ahi = *(const float4*)&aa2[c0+4];
    float4 blo = *(const float4*)&bb2[c0], bhi = *(const float4*)&bb2[c0+4];
    av[0]=alo.x; av[1]=alo.y; av[2]=alo.z; av[3]=alo.w;
    av[4]=ahi.x; av[5]=ahi.y; av[6]=ahi.z; av[7]=ahi.w;
    bv[0]=blo.x; bv[1]=blo.y; bv[2]=blo.z; bv[3]=blo.w;
    bv[4]=bhi.x; bv[5]=bhi.y; bv[6]=bhi.z; bv[7]=bhi.w;
  }
#pragma unroll
  for (int i = 0; i < 4; ++i) {
    int off = t*8 + i*2048;
    half8 v = ldv(&z[chunk + off]);
    half8 y;
#pragma unroll
    for (int jj = 0; jj < 8; ++jj)
      y[jj] = (_Float16)fmaxf(av[jj]*(float)v[jj] + bv[jj], 0.f);
    *(half8*)&s2[(off>>7)*P1 + c0] = y;
  }
  __syncthreads();

  int w = t >> 6, l = t & 63;
  int lr = l & 15, lg = l >> 4;
  int ko = lg * 8;
  int arow = w*16 + lr;

  half8 g0 = ldv(&s2[arow*P1 +  0 + ko]);
  half8 g1 = ldv(&s2[arow*P1 + 32 + ko]);
  half8 g2 = ldv(&s2[arow*P1 + 64 + ko]);
  half8 g3 = ldv(&s2[arow*P1 + 96 + ko]);
  f32x4 acc3[16];
#pragma unroll
  for (int n = 0; n < 16; ++n) {
    const ushort_t* wrow = wb3 + (size_t)(n*16 + lr)*128 + ko;
    f32x4 c = {0.f,0.f,0.f,0.f};
    c = MF(g0, ldv(wrow +  0), c);
    c = MF(g1, ldv(wrow + 32), c);
    c = MF(g2, ldv(wrow + 64), c);
    c = MF(g3, ldv(wrow + 96), c);
    acc3[n] = c;
  }

#pragma unroll
  for (int n = 0; n < 16; ++n) {
    int c = n*16 + lr;
    float bi = bias3[c];
    float x0 = acc3[n][0]+bi, x1 = acc3[n][1]+bi, x2 = acc3[n][2]+bi, x3 = acc3[n][3]+bi;
    float s4 = (x0+x1)+(x2+x3);
    float q4 = (x0*x0+x1*x1)+(x2*x2+x3*x3);
    s4 += __shfl_xor(s4, 16); s4 += __shfl_xor(s4, 32);
    q4 += __shfl_xor(q4, 16); q4 += __shfl_xor(q4, 32);
    float mx = fmaxf(fmaxf(x0,x1), fmaxf(x2,x3));
    float mn = fminf(fminf(x0,x1), fminf(x2,x3));
    mx = fmaxf(mx, __shfl_xor(mx, 16)); mx = fmaxf(mx, __shfl_xor(mx, 32));
    mn = fminf(mn, __shfl_xor(mn, 16)); mn = fminf(mn, __shfl_xor(mn, 32));
    if (lg == 0) {
      sred[w][c][0] = s4; sred[w][c][1] = q4;
      smm[w][c][0] = mx; smm[w][c][1] = mn;
    }
  }
  __syncthreads();
  if (t < 256) {
    float ps = (sred[0][t][0]+sred[1][t][0])+(sred[2][t][0]+sred[3][t][0]);
    float pq = (sred[0][t][1]+sred[1][t][1])+(sred[2][t][1]+sred[3][t][1]);
    psum[(size_t)t*NBLK + blk] = ps;
    psq [(size_t)t*NBLK + blk] = pq;
#pragma unroll
    for (int gi2 = 0; gi2 < 2; ++gi2) {
      float mx = fmaxf(smm[gi2*2][t][0], smm[gi2*2+1][t][0]);
      float mn = fminf(smm[gi2*2][t][1], smm[gi2*2+1][t][1]);
      size_t o = ((size_t)(b*256 + t))*SS + (pr*2 + gi2);
      maxb[o] = mx; minb[o] = mn;
    }
  }
}

// ---------- 4-fallback. fused conv chain (recompute prefix) ----------
template<int DEPTH>
__global__ __launch_bounds__(256) void fused_kernel(
    const float* __restrict__ xyz, const float* __restrict__ points,
    const float* __restrict__ newxyz, const int* __restrict__ nn,
    const ushort_t* __restrict__ wb1, const ushort_t* __restrict__ wb2,
    const ushort_t* __restrict__ wb3,
    const float* __restrict__ bias1, const float* __restrict__ bias2,
    const float* __restrict__ bias3,
    const float* __restrict__ aa1, const float* __restrict__ bb1,
    const float* __restrict__ aa2, const float* __restrict__ bb2,
    float* __restrict__ psum, float* __restrict__ psq,
    float* __restrict__ maxb, float* __restrict__ minb)
{
  __shared__ __align__(16) ushort_t sF[64*P0];
  __shared__ __align__(16) ushort_t s1[(DEPTH>=2) ? 64*P1 : 8];
  __shared__ __align__(16) ushort_t s2[(DEPTH>=3) ? 64*P1 : 8];
  __shared__ float sred[4][256][2];
  __shared__ float smm[(DEPTH>=3)?4:1][256][2];

  int t = threadIdx.x, blk = blockIdx.x;
  int b = blk >> 9, pr = blk & 511;

  stage_feat0(xyz, points, newxyz, nn, sF, t, b, pr);
  __syncthreads();

  int w = t >> 6, l = t & 63;
  int lr = l & 15, lg = l >> 4;
  int ko = lg * 8;
  int arow = w*16 + lr;

  half8 a0 = ldv(&sF[arow*P0 +  0 + ko]);
  half8 a1 = ldv(&sF[arow*P0 + 32 + ko]);
  half8 a2 = ldv(&sF[arow*P0 + 64 + ko]);
  f32x4 acc1[8];
#pragma unroll
  for (int n = 0; n < 8; ++n) {
    const ushort_t* wrow = wb1 + (size_t)(n*16 + lr)*96 + ko;
    f32x4 c = {0.f,0.f,0.f,0.f};
    c = MF(a0, ldv(wrow +  0), c);
    c = MF(a1, ldv(wrow + 32), c);
    c = MF(a2, ldv(wrow + 64), c);
    acc1[n] = c;
  }

  if constexpr (DEPTH == 1) {
    stats_and_store<8>(acc1, bias1, sred, w, lr, lg, t, blk, psum, psq);
  } else {
#pragma unroll
    for (int n = 0; n < 8; ++n) {
      int c = n*16 + lr;
      float a = aa1[c], bo = bb1[c], bi = bias1[c];
#pragma unroll
      for (int rr = 0; rr < 4; ++rr) {
        float y = fmaxf(a*(acc1[n][rr] + bi) + bo, 0.f);
        s1[(w*16 + lg*4 + rr)*P1 + c] = f2h(y);
      }
    }
    __syncthreads();

    half8 f0 = ldv(&s1[arow*P1 +  0 + ko]);
    half8 f1 = ldv(&s1[arow*P1 + 32 + ko]);
    half8 f2 = ldv(&s1[arow*P1 + 64 + ko]);
    half8 f3 = ldv(&s1[arow*P1 + 96 + ko]);
    f32x4 acc2[8];
#pragma unroll
    for (int n = 0; n < 8; ++n) {
      const ushort_t* wrow = wb2 + (size_t)(n*16 + lr)*128 + ko;
      f32x4 c = {0.f,0.f,0.f,0.f};
      c = MF(f0, ldv(wrow +  0), c);
      c = MF(f1, ldv(wrow + 32), c);
      c = MF(f2, ldv(wrow + 64), c);
      c = MF(f3, ldv(wrow + 96), c);
      acc2[n] = c;
    }

    if constexpr (DEPTH == 2) {
      stats_and_store<8>(acc2, bias2, sred, w, lr, lg, t, blk, psum, psq);
    } else {
#pragma unroll
      for (int n = 0; n < 8; ++n) {
        int c = n*16 + lr;
        float a = aa2[c], bo = bb2[c], bi = bias2[c];
#pragma unroll
        for (int rr = 0; rr < 4; ++rr) {
          float y = fmaxf(a*(acc2[n][rr] + bi) + bo, 0.f);
          s2[(w*16 + lg*4 + rr)*P1 + c] = f2h(y);
        }
      }
      __syncthreads();

      half8 g0 = ldv(&s2[arow*P1 +  0 + ko]);
      half8 g1 = ldv(&s2[arow*P1 + 32 + ko]);
      half8 g2 = ldv(&s2[arow*P1 + 64 + ko]);
      half8 g3 = ldv(&s2[arow*P1 + 96 + ko]);
      f32x4 acc3[16];
#pragma unroll
      for (int n = 0; n < 16; ++n) {
        const ushort_t* wrow = wb3 + (size_t)(n*16 + lr)*128 + ko;
        f32x4 c = {0.f,0.f,0.f,0.f};
        c = MF(g0, ldv(wrow +  0), c);
        c = MF(g1, ldv(wrow + 32), c);
        c = MF(g2, ldv(wrow + 64), c);
        c = MF(g3, ldv(wrow + 96), c);
        acc3[n] = c;
      }

#pragma unroll
      for (int n = 0; n < 16; ++n) {
        int c = n*16 + lr;
        float bi = bias3[c];
        float x0 = acc3[n][0]+bi, x1 = acc3[n][1]+bi, x2 = acc3[n][2]+bi, x3 = acc3[n][3]+bi;
        float s4 = (x0+x1)+(x2+x3);
        float q4 = (x0*x0+x1*x1)+(x2*x2+x3*x3);
        s4 += __shfl_xor(s4, 16); s4 += __shfl_xor(s4, 32);
        q4 += __shfl_xor(q4, 16); q4 += __shfl_xor(q4, 32);
        float mx = fmaxf(fmaxf(x0,x1), fmaxf(x2,x3));
        float mn = fminf(fminf(x0,x1), fminf(x2,x3));
        mx = fmaxf(mx, __shfl_xor(mx, 16)); mx = fmaxf(mx, __shfl_xor(mx, 32));
        mn = fminf(mn, __shfl_xor(mn, 16)); mn = fminf(mn, __shfl_xor(mn, 32));
        if (lg == 0) {
          sred[w][c][0] = s4; sred[w][c][1] = q4;
          smm[w][c][0] = mx; smm[w][c][1] = mn;
        }
      }
      __syncthreads();
      if (t < 256) {
        float ps = (sred[0][t][0]+sred[1][t][0])+(sred[2][t][0]+sred[3][t][0]);
        float pq = (sred[0][t][1]+sred[1][t][1])+(sred[2][t][1]+sred[3][t][1]);
        psum[(size_t)t*NBLK + blk] = ps;
        psq [(size_t)t*NBLK + blk] = pq;
#pragma unroll
        for (int gi2 = 0; gi2 < 2; ++gi2) {
          float mx = fmaxf(smm[gi2*2][t][0], smm[gi2*2+1][t][0]);
          float mn = fminf(smm[gi2*2][t][1], smm[gi2*2+1][t][1]);
          size_t o = ((size_t)(b*256 + t))*SS + (pr*2 + gi2);
          maxb[o] = mx; minb[o] = mn;
        }
      }
    }
  }
}

// ---------- 5. finalize BN stats -> affine a,b (optional bias fold) ----------
__global__ __launch_bounds__(256) void bnstats_finalize_kernel(
    const float* __restrict__ psum, const float* __restrict__ psq,
    const float* __restrict__ gamma, const float* __restrict__ beta,
    const float* __restrict__ bias, int fold,
    float* __restrict__ aa, float* __restrict__ bb)
{
  int c = blockIdx.x, t = threadIdx.x;
  double s = 0.0, q = 0.0;
  for (int i = t; i < NBLK; i += 256) {
    s += (double)psum[(size_t)c*NBLK + i];
    q += (double)psq [(size_t)c*NBLK + i];
  }
#pragma unroll
  for (int m = 1; m <= 32; m <<= 1) { s += __shfl_xor(s, m); q += __shfl_xor(q, m); }
  __shared__ double sd[4][2];
  if ((t & 63) == 0) { sd[t>>6][0] = s; sd[t>>6][1] = q; }
  __syncthreads();
  if (t == 0) {
    double S = (sd[0][0]+sd[1][0])+(sd[2][0]+sd[3][0]);
    double Q = (sd[0][1]+sd[1][1])+(sd[2][1]+sd[3][1]);
    double mean = S / (double)MTOT;
    double var  = Q / (double)MTOT - mean*mean;
    double rs = 1.0 / sqrt(var + 1e-5);
    double a = (double)gamma[c] * rs;
    aa[c] = (float)a;
    double bbv = (double)beta[c] - mean * a;
    if (fold) bbv += a * (double)bias[c];
    bb[c] = (float)bbv;
  }
}

// ---------- 6. final output ----------
__global__ __launch_bounds__(256) void final_out_kernel(
    const float* __restrict__ aa, const float* __restrict__ bb,
    const float* __restrict__ maxb, const float* __restrict__ minb,
    float* __restrict__ out2)
{
  int blk = blockIdx.x;            // b*256 + c
  int c = blk & 255;
  float a = aa[c], bo = bb[c];
  const float* src = (a >= 0.f) ? maxb : minb;
  size_t base = (size_t)blk * SS;
  for (int s = threadIdx.x; s < SS; s += 256)
    out2[base + s] = fmaxf(fmaf(a, src[base + s], bo), 0.f);
}

// ---------- launch ----------
extern "C" void kernel_launch(void* const* d_in, const int* in_sizes, int n_in,
                              void* d_out, int out_size, void* d_ws, size_t ws_size,
                              hipStream_t stream) {
  const float* xyz    = (const float*)d_in[0];
  const float* points = (const float*)d_in[1];
  const float* W0 = (const float*)d_in[2];
  const float* b0 = (const float*)d_in[3];
  const float* g0 = (const float*)d_in[4];
  const float* be0= (const float*)d_in[5];
  const float* W1 = (const float*)d_in[6];
  const float* b1 = (const float*)d_in[7];
  const float* g1 = (const float*)d_in[8];
  const float* be1= (const float*)d_in[9];
  const float* W2 = (const float*)d_in[10];
  const float* b2 = (const float*)d_in[11];
  const float* g2 = (const float*)d_in[12];
  const float* be2= (const float*)d_in[13];

  float* out = (float*)d_out;
  float* newxyz = out;                 // (8,1024,3)
  float* out2   = out + BB*SS*3;       // (8,256,1024)

  char* ws = (char*)d_ws;
  int*      nn   = (int*)ws;
  ushort_t* wb1  = (ushort_t*)(ws + 0x100000);
  ushort_t* wb2  = (ushort_t*)(ws + 0x106000);
  ushort_t* wb3  = (ushort_t*)(ws + 0x10E000);
  float* aa1 = (float*)(ws + 0x11E000);
  float* bb1 = aa1 + 128;
  float* aa2 = bb1 + 128;
  float* bb2 = aa2 + 128;
  float* aa3 = bb2 + 128;
  float* bb3 = aa3 + 256;
  float* psum1 = (float*)(ws + 0x120000);
  float* psq1  = (float*)(ws + 0x320000);
  float* psum2 = (float*)(ws + 0x520000);
  float* psq2  = (float*)(ws + 0x720000);
  float* psum3 = (float*)(ws + 0x920000);
  float* psq3  = (float*)(ws + 0xD20000);
  float* maxb  = (float*)(ws + 0x1120000);
  float* minb  = (float*)(ws + 0x1920000);
  ushort_t* z  = (ushort_t*)(ws + 0x2120000);     // 64 MB f16 activations
  const size_t NEEDED = 0x6120000ull;

  prep_kernel<<<64, 256, 0, stream>>>(W0, W1, W2, wb1, wb2, wb3);
  fps_kernel<<<BB, 512, 0, stream>>>(xyz, newxyz);
  knn_kernel<<<BB*SS, 256, 0, stream>>>(xyz, newxyz, nn);

  if (ws_size >= NEEDED) {
    conv1_kernel<<<NBLK, 256, 0, stream>>>(xyz, points, newxyz, nn, wb1, b0,
                                           z, psum1, psq1);
    bnstats_finalize_kernel<<<O1, 256, 0, stream>>>(psum1, psq1, g0, be0, b0, 1, aa1, bb1);
    conv2_kernel<<<NBLK, 256, 0, stream>>>(z, wb2, b1, aa1, bb1, psum2, psq2);
    bnstats_finalize_kernel<<<O2, 256, 0, stream>>>(psum2, psq2, g1, be1, b1, 1, aa2, bb2);
    conv3_kernel<<<NBLK, 256, 0, stream>>>(z, wb3, b2, aa2, bb2, psum3, psq3, maxb, minb);
    bnstats_finalize_kernel<<<O3, 256, 0, stream>>>(psum3, psq3, g2, be2, b2, 0, aa3, bb3);
  } else {
    fused_kernel<1><<<NBLK, 256, 0, stream>>>(xyz, points, newxyz, nn, wb1, wb2, wb3,
        b0, b1, b2, aa1, bb1, aa2, bb2, psum1, psq1, maxb, minb);
    bnstats_finalize_kernel<<<O1, 256, 0, stream>>>(psum1, psq1, g0, be0, b0, 0, aa1, bb1);
    fused_kernel<2><<<NBLK, 256, 0, stream>>>(xyz, points, newxyz, nn, wb1, wb2, wb3,
        b0, b1, b2, aa1, bb1, aa2, bb2, psum2, psq2, maxb, minb);
    bnstats_finalize_kernel<<<O2, 256, 0, stream>>>(psum2, psq2, g1, be1, b1, 0, aa2, bb2);
    fused_kernel<3><<<NBLK, 256, 0, stream>>>(xyz, points, newxyz, nn, wb1, wb2, wb3,
        b0, b1, b2, aa1, bb1, aa2, bb2, psum3, psq3, maxb, minb);
    bnstats_finalize_kernel<<<O3, 256, 0, stream>>>(psum3, psq3, g2, be2, b2, 0, aa3, bb3);
  }

  final_out_kernel<<<BB*O3, 256, 0, stream>>>(aa3, bb3, maxb, minb, out2);
}

// Round 7
// 1742.821 us; speedup vs baseline: 1.0301x; 1.0301x over previous
//
#include <hip/hip_runtime.h>
#include <cstdint>
#include <cstddef>

typedef _Float16 half8 __attribute__((ext_vector_type(8)));
typedef float f32x4 __attribute__((ext_vector_type(4)));
typedef unsigned short ushort_t;

// ---------- constants ----------
#define BB 8
#define NN 4096
#define CIN 64
#define SS 1024
#define KK 32
#define O1 128
#define O2 128
#define O3 256
#define C0 67          // 3 + CIN
#define P0 104         // LDS pitch for feat0 (odd multiple of 8 halves = 16B)
#define P1 136         // LDS pitch for activations (odd multiple of 8 halves)
#define MTOT (BB*SS*KK)   // 262144 rows
#define NBLK 4096         // fused grid: B * S/2

// ---------- helpers ----------
__device__ __forceinline__ ushort_t f2h(float v) {
  union { _Float16 h; ushort_t u; } cv;
  cv.h = (_Float16)v;
  return cv.u;
}
__device__ __forceinline__ half8 ldv(const ushort_t* p) {
  return *(const half8*)p;
}
__device__ __forceinline__ f32x4 MF(half8 a, half8 b, f32x4 c) {
  return __builtin_amdgcn_mfma_f32_16x16x32_f16(a, b, c, 0, 0, 0);
}

// ---- DPP-only 64-lane (value, idx) reduce; result lands in LANE 63.
// MAXM=true: argmax (ties -> smaller idx). MAXM=false: argmin (ties -> smaller idx).
template<bool MAXM>
__device__ __forceinline__ void wave_red_dpp(float& d, int& i) {
#define RED_TAKE(d2, i2) \
  { bool take = MAXM ? ((d2) > d || ((d2) == d && (i2) < i)) \
                     : ((d2) < d || ((d2) == d && (i2) < i)); \
    if (take) { d = (d2); i = (i2); } }
#define RED_DPP(CTRL) \
  { float d2_ = __int_as_float(__builtin_amdgcn_update_dpp(0, __float_as_int(d), CTRL, 0xf, 0xf, true)); \
    int   i2_ = __builtin_amdgcn_update_dpp(0, i, CTRL, 0xf, 0xf, true); \
    RED_TAKE(d2_, i2_) }
  RED_DPP(0x128)   // row_ror:8
  RED_DPP(0x124)   // row_ror:4
  RED_DPP(0x122)   // row_ror:2
  RED_DPP(0x121)   // row_ror:1
  RED_DPP(0x142)   // row_bcast:15
  RED_DPP(0x143)   // row_bcast:31
#undef RED_DPP
#undef RED_TAKE
}

// ---------- 1. FPS: one block (128 thr, 2 waves) per batch ----------
__global__ __launch_bounds__(128, 1) void fps_kernel(const float* __restrict__ xyz,
                                                     float* __restrict__ newxyz) {
  int b = blockIdx.x, t = threadIdx.x;
  __shared__ float sxyz[NN*3];
  __shared__ float snew[SS*3];                    // centroid buffer
  __shared__ __align__(16) float wpair[2][2][2];  // [parity][wave][{dist, idx-bits}]
  {
    const float4* src = (const float4*)(xyz + (size_t)b * (NN*3));
    float4* dst = (float4*)sxyz;
    for (int i = t; i < NN*3/4; i += 128) dst[i] = src[i];
  }
  __syncthreads();
  float px[32], py[32], pz[32], dist[32];
#pragma unroll
  for (int j = 0; j < 32; ++j) {
    int n = t + 128*j;
    px[j] = sxyz[n*3+0]; py[j] = sxyz[n*3+1]; pz[j] = sxyz[n*3+2];
    dist[j] = 1e10f;
  }
  float cx = sxyz[0], cy = sxyz[1], cz = sxyz[2];
  for (int s = 0; s < SS; ++s) {
    if (t == 0) {
      snew[s*3+0] = cx; snew[s*3+1] = cy; snew[s*3+2] = cz;
    }
    // distance + 8 independent argmax chains (dep depth 4)
    float bd[8]; int bi[8];
#pragma unroll
    for (int ch = 0; ch < 8; ++ch) { bd[ch] = -1.f; bi[ch] = 0; }
#pragma unroll
    for (int j = 0; j < 32; ++j) {
      // exact np order: ((dx*dx + dy*dy) + dz*dz), no FMA contraction
      float dx = __fadd_rn(px[j], -cx);
      float dy = __fadd_rn(py[j], -cy);
      float dz = __fadd_rn(pz[j], -cz);
      float d = __fadd_rn(__fadd_rn(__fmul_rn(dx,dx), __fmul_rn(dy,dy)), __fmul_rn(dz,dz));
      float nd = fminf(dist[j], d);
      dist[j] = nd;
      int idx = t + 128*j;
      // within a chain j increases -> strict > keeps first (smallest) index on tie
      int ch = j & 7;   // compile-time constant in unrolled body
      if (nd > bd[ch]) { bd[ch] = nd; bi[ch] = idx; }
    }
    // combine 8 chains (tree), tie-break by smaller index (np.argmax = first max)
#define CMB2(D0,I0,D1,I1) { if ((D1) > (D0) || ((D1) == (D0) && (I1) < (I0))) { D0 = D1; I0 = I1; } }
    CMB2(bd[0],bi[0],bd[1],bi[1]) CMB2(bd[2],bi[2],bd[3],bi[3])
    CMB2(bd[4],bi[4],bd[5],bi[5]) CMB2(bd[6],bi[6],bd[7],bi[7])
    CMB2(bd[0],bi[0],bd[2],bi[2]) CMB2(bd[4],bi[4],bd[6],bi[6])
    CMB2(bd[0],bi[0],bd[4],bi[4])
#undef CMB2
    float bdv = bd[0]; int biv = bi[0];

    wave_red_dpp<true>(bdv, biv);     // result in lane 63

    int p = s & 1;
    if ((t & 63) == 63) {
      wpair[p][t>>6][0] = bdv;
      ((int*)&wpair[p][t>>6][0])[1] = biv;
    }
    __syncthreads();
    // one float4 read gets both wave partials
    float4 q = *(const float4*)&wpair[p][0][0];
    float fd = q.x; int fi = __float_as_int(q.y);
    {
      float od = q.z; int oi = __float_as_int(q.w);
      if (od > fd || (od == fd && oi < fi)) { fd = od; fi = oi; }
    }
    cx = sxyz[fi*3+0]; cy = sxyz[fi*3+1]; cz = sxyz[fi*3+2];
  }
  __syncthreads();
  { // coalesced write-out of all centroids
    float4* dst = (float4*)(newxyz + (size_t)b * (SS*3));
    const float4* src = (const float4*)snew;
    for (int i = t; i < SS*3/4; i += 128) dst[i] = src[i];
  }
}

// ---------- 2. KNN: one block per query, extract-min 32x ----------
__global__ __launch_bounds__(256) void knn_kernel(const float* __restrict__ xyz,
                                                  const float* __restrict__ newxyz,
                                                  int* __restrict__ nn) {
  int blk = blockIdx.x;           // b*1024 + s
  int b = blk >> 10;
  int t = threadIdx.x;
  __shared__ float ld[2][4];
  __shared__ int   li[2][4];
  float qx = newxyz[(size_t)blk*3+0];
  float qy = newxyz[(size_t)blk*3+1];
  float qz = newxyz[(size_t)blk*3+2];
  float cs = __fadd_rn(__fadd_rn(__fmul_rn(qx,qx), __fmul_rn(qy,qy)), __fmul_rn(qz,qz));
  const float* base = xyz + (size_t)b * (NN*3);
  float d[16];
#pragma unroll
  for (int j = 0; j < 16; ++j) {
    int n = t + 256*j;
    float px = base[n*3+0], py = base[n*3+1], pz = base[n*3+2];
    float xs  = __fadd_rn(__fadd_rn(__fmul_rn(px,px), __fmul_rn(py,py)), __fmul_rn(pz,pz));
    float dot = __fadd_rn(__fadd_rn(__fmul_rn(qx,px), __fmul_rn(qy,py)), __fmul_rn(qz,pz));
    // reference: (cs - 2*dot) + xs
    d[j] = __fadd_rn(__fadd_rn(cs, -__fmul_rn(2.f, dot)), xs);
  }
  int* myout = nn + (size_t)blk * KK;
  for (int it = 0; it < KK; ++it) {
    float bd = 3.0e38f; int bi = 0x7fffffff;
#pragma unroll
    for (int j = 0; j < 16; ++j) {
      if (d[j] < bd) { bd = d[j]; bi = t + 256*j; }   // strict < keeps smaller idx
    }
    wave_red_dpp<false>(bd, bi);    // result in lane 63
    int p = it & 1;
    if ((t & 63) == 63) { ld[p][t>>6] = bd; li[p][t>>6] = bi; }
    __syncthreads();
    float fd = ld[p][0]; int fi = li[p][0];
#pragma unroll
    for (int w2 = 1; w2 < 4; ++w2) {
      float od = ld[p][w2]; int oi = li[p][w2];
      if (od < fd || (od == fd && oi < fi)) { fd = od; fi = oi; }
    }
    if ((fi & 255) == t) {
      int jj = fi >> 8;
#pragma unroll
      for (int j = 0; j < 16; ++j) if (j == jj) d[j] = 3.0e38f;
    }
    if (t == 0) myout[it] = fi;
  }
}

// ---------- 3. weights fp32 -> fp16, zero-padded ----------
__global__ void prep_kernel(const float* __restrict__ W0, const float* __restrict__ W1,
                            const float* __restrict__ W2,
                            ushort_t* __restrict__ wb1, ushort_t* __restrict__ wb2,
                            ushort_t* __restrict__ wb3) {
  int i = blockIdx.x*256 + threadIdx.x;
  int stride = gridDim.x*256;
  const int n1 = O1*96, n2 = O2*128, n3 = O3*128;
  for (; i < n1+n2+n3; i += stride) {
    if (i < n1) {
      int o = i / 96, k = i - o*96;
      wb1[i] = (k < C0) ? f2h(W0[o*C0 + k]) : (ushort_t)0;
    } else if (i < n1+n2) {
      int j = i - n1;
      wb2[j] = f2h(W1[j]);
    } else {
      int j = i - n1 - n2;
      wb3[j] = f2h(W2[j]);
    }
  }
}

// ---------- shared epilogue helper (fallback path) ----------
template<int NT>
__device__ __forceinline__ void stats_and_store(
    const f32x4* acc, const float* __restrict__ bias,
    float (*sred)[256][2],
    int w, int lr, int lg, int t, int blk,
    float* __restrict__ psum, float* __restrict__ psq)
{
#pragma unroll
  for (int n = 0; n < NT; ++n) {
    int c = n*16 + lr;
    float bi = bias[c];
    float x0 = acc[n][0]+bi, x1 = acc[n][1]+bi, x2 = acc[n][2]+bi, x3 = acc[n][3]+bi;
    float s4 = (x0+x1)+(x2+x3);
    float q4 = (x0*x0+x1*x1)+(x2*x2+x3*x3);
    s4 += __shfl_xor(s4, 16); s4 += __shfl_xor(s4, 32);
    q4 += __shfl_xor(q4, 16); q4 += __shfl_xor(q4, 32);
    if (lg == 0) { sred[w][c][0] = s4; sred[w][c][1] = q4; }
  }
  __syncthreads();
  if (t < NT*16) {
    float ps = (sred[0][t][0]+sred[1][t][0])+(sred[2][t][0]+sred[3][t][0]);
    float pq = (sred[0][t][1]+sred[1][t][1])+(sred[2][t][1]+sred[3][t][1]);
    psum[(size_t)t*NBLK + blk] = ps;
    psq [(size_t)t*NBLK + blk] = pq;
  }
}

// ---------- feat0 staging (shared by conv1 + fallback) ----------
__device__ __forceinline__ void stage_feat0(
    const float* __restrict__ xyz, const float* __restrict__ points,
    const float* __restrict__ newxyz, const int* __restrict__ nn,
    ushort_t* sF, int t, int b, int pr)
{
  int r = t >> 2, q = t & 3;
  int gi = r >> 5, j = r & 31;
  int bs = (b << 10) + (pr*2 + gi);
  int idx = nn[(size_t)bs*KK + j];
  const float* prow = points + ((size_t)(b*NN + idx))*CIN;
  const float* pxyz = xyz    + ((size_t)(b*NN + idx))*3;
  const float* ctr  = newxyz + (size_t)bs*3;
  ushort_t* dst = &sF[r*P0];
  if (q < 3) dst[q] = f2h(pxyz[q] - ctr[q]);
#pragma unroll
  for (int ii = 0; ii < 4; ++ii) {
    float4 v = *(const float4*)&prow[q*4 + ii*16];
    int c = 3 + q*4 + ii*16;
    dst[c+0] = f2h(v.x); dst[c+1] = f2h(v.y); dst[c+2] = f2h(v.z); dst[c+3] = f2h(v.w);
  }
  for (int c = C0 + q; c < P0; c += 4) dst[c] = 0;
}

// ---------- 4a. conv1 (materialized): feat0 -> conv1 -> z + stats1 ----------
__global__ __launch_bounds__(256) void conv1_kernel(
    const float* __restrict__ xyz, const float* __restrict__ points,
    const float* __restrict__ newxyz, const int* __restrict__ nn,
    const ushort_t* __restrict__ wb1, const float* __restrict__ bias1,
    ushort_t* __restrict__ z, float* __restrict__ psum, float* __restrict__ psq)
{
  __shared__ __align__(16) ushort_t sF[64*P0];
  __shared__ __align__(16) ushort_t s1[64*P1];
  __shared__ float sred[4][O1][2];
  int t = threadIdx.x, blk = blockIdx.x;
  int b = blk >> 9, pr = blk & 511;

  stage_feat0(xyz, points, newxyz, nn, sF, t, b, pr);
  __syncthreads();

  int w = t >> 6, l = t & 63;
  int lr = l & 15, lg = l >> 4;
  int ko = lg * 8;
  int arow = w*16 + lr;

  half8 a0 = ldv(&sF[arow*P0 +  0 + ko]);
  half8 a1 = ldv(&sF[arow*P0 + 32 + ko]);
  half8 a2 = ldv(&sF[arow*P0 + 64 + ko]);
  f32x4 acc1[8];
#pragma unroll
  for (int n = 0; n < 8; ++n) {
    const ushort_t* wrow = wb1 + (size_t)(n*16 + lr)*96 + ko;
    f32x4 c = {0.f,0.f,0.f,0.f};
    c = MF(a0, ldv(wrow +  0), c);
    c = MF(a1, ldv(wrow + 32), c);
    c = MF(a2, ldv(wrow + 64), c);
    acc1[n] = c;
  }

  // epilogue: raw acc -> s1 (for coalesced z store), stats on acc+bias
#pragma unroll
  for (int n = 0; n < 8; ++n) {
    int c = n*16 + lr;
#pragma unroll
    for (int rr = 0; rr < 4; ++rr)
      s1[(w*16 + lg*4 + rr)*P1 + c] = f2h(acc1[n][rr]);
    float bi = bias1[c];
    float x0 = acc1[n][0]+bi, x1 = acc1[n][1]+bi, x2 = acc1[n][2]+bi, x3 = acc1[n][3]+bi;
    float s4 = (x0+x1)+(x2+x3);
    float q4 = (x0*x0+x1*x1)+(x2*x2+x3*x3);
    s4 += __shfl_xor(s4, 16); s4 += __shfl_xor(s4, 32);
    q4 += __shfl_xor(q4, 16); q4 += __shfl_xor(q4, 32);
    if (lg == 0) { sred[w][c][0] = s4; sred[w][c][1] = q4; }
  }
  __syncthreads();
  { // coalesced z store: 64 rows x 128 halves
    size_t chunk = (size_t)blk * (64*128);
#pragma unroll
    for (int i = 0; i < 4; ++i) {
      int off = t*8 + i*2048;
      *(half8*)&z[chunk + off] = ldv(&s1[(off>>7)*P1 + (off&127)]);
    }
  }
  if (t < O1) {
    float ps = (sred[0][t][0]+sred[1][t][0])+(sred[2][t][0]+sred[3][t][0]);
    float pq = (sred[0][t][1]+sred[1][t][1])+(sred[2][t][1]+sred[3][t][1]);
    psum[(size_t)t*NBLK + blk] = ps;
    psq [(size_t)t*NBLK + blk] = pq;
  }
}

// ---------- 4b. conv2 (materialized): z -> affine1+relu -> conv2 -> z + stats2 ----------
__global__ __launch_bounds__(256) void conv2_kernel(
    ushort_t* __restrict__ z, const ushort_t* __restrict__ wb2,
    const float* __restrict__ bias2,
    const float* __restrict__ aa1, const float* __restrict__ bb1,
    float* __restrict__ psum, float* __restrict__ psq)
{
  __shared__ __align__(16) ushort_t s1[64*P1];
  __shared__ float sred[4][O2][2];
  int t = threadIdx.x, blk = blockIdx.x;
  size_t chunk = (size_t)blk * (64*128);

  int c0 = (t*8) & 127;
  float av[8], bv[8];
  {
    float4 alo = *(const float4*)&aa1[c0], ahi = *(const float4*)&aa1[c0+4];
    float4 blo = *(const float4*)&bb1[c0], bhi = *(const float4*)&bb1[c0+4];
    av[0]=alo.x; av[1]=alo.y; av[2]=alo.z; av[3]=alo.w;
    av[4]=ahi.x; av[5]=ahi.y; av[6]=ahi.z; av[7]=ahi.w;
    bv[0]=blo.x; bv[1]=blo.y; bv[2]=blo.z; bv[3]=blo.w;
    bv[4]=bhi.x; bv[5]=bhi.y; bv[6]=bhi.z; bv[7]=bhi.w;
  }
#pragma unroll
  for (int i = 0; i < 4; ++i) {
    int off = t*8 + i*2048;
    half8 v = ldv(&z[chunk + off]);
    half8 y;
#pragma unroll
    for (int jj = 0; jj < 8; ++jj)
      y[jj] = (_Float16)fmaxf(av[jj]*(float)v[jj] + bv[jj], 0.f);
    *(half8*)&s1[(off>>7)*P1 + c0] = y;
  }
  __syncthreads();

  int w = t >> 6, l = t & 63;
  int lr = l & 15, lg = l >> 4;
  int ko = lg * 8;
  int arow = w*16 + lr;

  half8 f0 = ldv(&s1[arow*P1 +  0 + ko]);
  half8 f1 = ldv(&s1[arow*P1 + 32 + ko]);
  half8 f2 = ldv(&s1[arow*P1 + 64 + ko]);
  half8 f3 = ldv(&s1[arow*P1 + 96 + ko]);
  f32x4 acc2[8];
#pragma unroll
  for (int n = 0; n < 8; ++n) {
    const ushort_t* wrow = wb2 + (size_t)(n*16 + lr)*128 + ko;
    f32x4 c = {0.f,0.f,0.f,0.f};
    c = MF(f0, ldv(wrow +  0), c);
    c = MF(f1, ldv(wrow + 32), c);
    c = MF(f2, ldv(wrow + 64), c);
    c = MF(f3, ldv(wrow + 96), c);
    acc2[n] = c;
  }
  __syncthreads();   // all s1 frag reads done before overwrite

#pragma unroll
  for (int n = 0; n < 8; ++n) {
    int c = n*16 + lr;
#pragma unroll
    for (int rr = 0; rr < 4; ++rr)
      s1[(w*16 + lg*4 + rr)*P1 + c] = f2h(acc2[n][rr]);
    float bi = bias2[c];
    float x0 = acc2[n][0]+bi, x1 = acc2[n][1]+bi, x2 = acc2[n][2]+bi, x3 = acc2[n][3]+bi;
    float s4 = (x0+x1)+(x2+x3);
    float q4 = (x0*x0+x1*x1)+(x2*x2+x3*x3);
    s4 += __shfl_xor(s4, 16); s4 += __shfl_xor(s4, 32);
    q4 += __shfl_xor(q4, 16); q4 += __shfl_xor(q4, 32);
    if (lg == 0) { sred[w][c][0] = s4; sred[w][c][1] = q4; }
  }
  __syncthreads();
#pragma unroll
  for (int i = 0; i < 4; ++i) {
    int off = t*8 + i*2048;
    *(half8*)&z[chunk + off] = ldv(&s1[(off>>7)*P1 + (off&127)]);
  }
  if (t < O2) {
    float ps = (sred[0][t][0]+sred[1][t][0])+(sred[2][t][0]+sred[3][t][0]);
    float pq = (sred[0][t][1]+sred[1][t][1])+(sred[2][t][1]+sred[3][t][1]);
    psum[(size_t)t*NBLK + blk] = ps;
    psq [(size_t)t*NBLK + blk] = pq;
  }
}

// ---------- 4c. conv3 (materialized): z -> affine2+relu -> conv3 -> stats3 + max/min ----------
__global__ __launch_bounds__(256) void conv3_kernel(
    const ushort_t* __restrict__ z, const ushort_t* __restrict__ wb3,
    const float* __restrict__ bias3,
    const float* __restrict__ aa2, const float* __restrict__ bb2,
    float* __restrict__ psum, float* __restrict__ psq,
    float* __restrict__ maxb, float* __restrict__ minb)
{
  __shared__ __align__(16) ushort_t s2[64*P1];
  __shared__ float sred[4][O3][2];
  __shared__ float smm[4][O3][2];
  int t = threadIdx.x, blk = blockIdx.x;
  int b = blk >> 9, pr = blk & 511;
  size_t chunk = (size_t)blk * (64*128);

  int c0 = (t*8) & 127;
  float av[8], bv[8];
  {
    float4 alo = *(const float4*)&aa2[c0], ahi = *(const float4*)&aa2[c0+4];
    float4 blo = *(const float4*)&bb2[c0], bhi = *(const float4*)&bb2[c0+4];
    av[0]=alo.x; av[1]=alo.y; av[2]=alo.z; av[3]=alo.w;
    av[4]=ahi.x; av[5]=ahi.y; av[6]=ahi.z; av[7]=ahi.w;
    bv[0]=blo.x; bv[1]=blo.y; bv[2]=blo.z; bv[3]=blo.w;
    bv[4]=bhi.x; bv[5]=bhi.y; bv[6]=bhi.z; bv[7]=bhi.w;
  }
#pragma unroll
  for (int i = 0; i < 4; ++i) {
    int off = t*8 + i*2048;
    half8 v = ldv(&z[chunk + off]);
    half8 y;
#pragma unroll
    for (int jj = 0; jj < 8; ++jj)
      y[jj] = (_Float16)fmaxf(av[jj]*(float)v[jj] + bv[jj], 0.f);
    *(half8*)&s2[(off>>7)*P1 + c0] = y;
  }
  __syncthreads();

  int w = t >> 6, l = t & 63;
  int lr = l & 15, lg = l >> 4;
  int ko = lg * 8;
  int arow = w*16 + lr;

  half8 g0 = ldv(&s2[arow*P1 +  0 + ko]);
  half8 g1 = ldv(&s2[arow*P1 + 32 + ko]);
  half8 g2 = ldv(&s2[arow*P1 + 64 + ko]);
  half8 g3 = ldv(&s2[arow*P1 + 96 + ko]);
  f32x4 acc3[16];
#pragma unroll
  for (int n = 0; n < 16; ++n) {
    const ushort_t* wrow = wb3 + (size_t)(n*16 + lr)*128 + ko;
    f32x4 c = {0.f,0.f,0.f,0.f};
    c = MF(g0, ldv(wrow +  0), c);
    c = MF(g1, ldv(wrow + 32), c);
    c = MF(g2, ldv(wrow + 64), c);
    c = MF(g3, ldv(wrow + 96), c);
    acc3[n] = c;
  }

#pragma unroll
  for (int n = 0; n < 16; ++n) {
    int c = n*16 + lr;
    float bi = bias3[c];
    float x0 = acc3[n][0]+bi, x1 = acc3[n][1]+bi, x2 = acc3[n][2]+bi, x3 = acc3[n][3]+bi;
    float s4 = (x0+x1)+(x2+x3);
    float q4 = (x0*x0+x1*x1)+(x2*x2+x3*x3);
    s4 += __shfl_xor(s4, 16); s4 += __shfl_xor(s4, 32);
    q4 += __shfl_xor(q4, 16); q4 += __shfl_xor(q4, 32);
    float mx = fmaxf(fmaxf(x0,x1), fmaxf(x2,x3));
    float mn = fminf(fminf(x0,x1), fminf(x2,x3));
    mx = fmaxf(mx, __shfl_xor(mx, 16)); mx = fmaxf(mx, __shfl_xor(mx, 32));
    mn = fminf(mn, __shfl_xor(mn, 16)); mn = fminf(mn, __shfl_xor(mn, 32));
    if (lg == 0) {
      sred[w][c][0] = s4; sred[w][c][1] = q4;
      smm[w][c][0] = mx; smm[w][c][1] = mn;
    }
  }
  __syncthreads();
  if (t < 256) {
    float ps = (sred[0][t][0]+sred[1][t][0])+(sred[2][t][0]+sred[3][t][0]);
    float pq = (sred[0][t][1]+sred[1][t][1])+(sred[2][t][1]+sred[3][t][1]);
    psum[(size_t)t*NBLK + blk] = ps;
    psq [(size_t)t*NBLK + blk] = pq;
#pragma unroll
    for (int gi2 = 0; gi2 < 2; ++gi2) {
      float mx = fmaxf(smm[gi2*2][t][0], smm[gi2*2+1][t][0]);
      float mn = fminf(smm[gi2*2][t][1], smm[gi2*2+1][t][1]);
      size_t o = ((size_t)(b*256 + t))*SS + (pr*2 + gi2);
      maxb[o] = mx; minb[o] = mn;
    }
  }
}

// ---------- 4-fallback. fused conv chain (recompute prefix) ----------
template<int DEPTH>
__global__ __launch_bounds__(256) void fused_kernel(
    const float* __restrict__ xyz, const float* __restrict__ points,
    const float* __restrict__ newxyz, const int* __restrict__ nn,
    const ushort_t* __restrict__ wb1, const ushort_t* __restrict__ wb2,
    const ushort_t* __restrict__ wb3,
    const float* __restrict__ bias1, const float* __restrict__ bias2,
    const float* __restrict__ bias3,
    const float* __restrict__ aa1, const float* __restrict__ bb1,
    const float* __restrict__ aa2, const float* __restrict__ bb2,
    float* __restrict__ psum, float* __restrict__ psq,
    float* __restrict__ maxb, float* __restrict__ minb)
{
  __shared__ __align__(16) ushort_t sF[64*P0];
  __shared__ __align__(16) ushort_t s1[(DEPTH>=2) ? 64*P1 : 8];
  __shared__ __align__(16) ushort_t s2[(DEPTH>=3) ? 64*P1 : 8];
  __shared__ float sred[4][256][2];
  __shared__ float smm[(DEPTH>=3)?4:1][256][2];

  int t = threadIdx.x, blk = blockIdx.x;
  int b = blk >> 9, pr = blk & 511;

  stage_feat0(xyz, points, newxyz, nn, sF, t, b, pr);
  __syncthreads();

  int w = t >> 6, l = t & 63;
  int lr = l & 15, lg = l >> 4;
  int ko = lg * 8;
  int arow = w*16 + lr;

  half8 a0 = ldv(&sF[arow*P0 +  0 + ko]);
  half8 a1 = ldv(&sF[arow*P0 + 32 + ko]);
  half8 a2 = ldv(&sF[arow*P0 + 64 + ko]);
  f32x4 acc1[8];
#pragma unroll
  for (int n = 0; n < 8; ++n) {
    const ushort_t* wrow = wb1 + (size_t)(n*16 + lr)*96 + ko;
    f32x4 c = {0.f,0.f,0.f,0.f};
    c = MF(a0, ldv(wrow +  0), c);
    c = MF(a1, ldv(wrow + 32), c);
    c = MF(a2, ldv(wrow + 64), c);
    acc1[n] = c;
  }

  if constexpr (DEPTH == 1) {
    stats_and_store<8>(acc1, bias1, sred, w, lr, lg, t, blk, psum, psq);
  } else {
#pragma unroll
    for (int n = 0; n < 8; ++n) {
      int c = n*16 + lr;
      float a = aa1[c], bo = bb1[c], bi = bias1[c];
#pragma unroll
      for (int rr = 0; rr < 4; ++rr) {
        float y = fmaxf(a*(acc1[n][rr] + bi) + bo, 0.f);
        s1[(w*16 + lg*4 + rr)*P1 + c] = f2h(y);
      }
    }
    __syncthreads();

    half8 f0 = ldv(&s1[arow*P1 +  0 + ko]);
    half8 f1 = ldv(&s1[arow*P1 + 32 + ko]);
    half8 f2 = ldv(&s1[arow*P1 + 64 + ko]);
    half8 f3 = ldv(&s1[arow*P1 + 96 + ko]);
    f32x4 acc2[8];
#pragma unroll
    for (int n = 0; n < 8; ++n) {
      const ushort_t* wrow = wb2 + (size_t)(n*16 + lr)*128 + ko;
      f32x4 c = {0.f,0.f,0.f,0.f};
      c = MF(f0, ldv(wrow +  0), c);
      c = MF(f1, ldv(wrow + 32), c);
      c = MF(f2, ldv(wrow + 64), c);
      c = MF(f3, ldv(wrow + 96), c);
      acc2[n] = c;
    }

    if constexpr (DEPTH == 2) {
      stats_and_store<8>(acc2, bias2, sred, w, lr, lg, t, blk, psum, psq);
    } else {
#pragma unroll
      for (int n = 0; n < 8; ++n) {
        int c = n*16 + lr;
        float a = aa2[c], bo = bb2[c], bi = bias2[c];
#pragma unroll
        for (int rr = 0; rr < 4; ++rr) {
          float y = fmaxf(a*(acc2[n][rr] + bi) + bo, 0.f);
          s2[(w*16 + lg*4 + rr)*P1 + c] = f2h(y);
        }
      }
      __syncthreads();

      half8 g0 = ldv(&s2[arow*P1 +  0 + ko]);
      half8 g1 = ldv(&s2[arow*P1 + 32 + ko]);
      half8 g2 = ldv(&s2[arow*P1 + 64 + ko]);
      half8 g3 = ldv(&s2[arow*P1 + 96 + ko]);
      f32x4 acc3[16];
#pragma unroll
      for (int n = 0; n < 16; ++n) {
        const ushort_t* wrow = wb3 + (size_t)(n*16 + lr)*128 + ko;
        f32x4 c = {0.f,0.f,0.f,0.f};
        c = MF(g0, ldv(wrow +  0), c);
        c = MF(g1, ldv(wrow + 32), c);
        c = MF(g2, ldv(wrow + 64), c);
        c = MF(g3, ldv(wrow + 96), c);
        acc3[n] = c;
      }

#pragma unroll
      for (int n = 0; n < 16; ++n) {
        int c = n*16 + lr;
        float bi = bias3[c];
        float x0 = acc3[n][0]+bi, x1 = acc3[n][1]+bi, x2 = acc3[n][2]+bi, x3 = acc3[n][3]+bi;
        float s4 = (x0+x1)+(x2+x3);
        float q4 = (x0*x0+x1*x1)+(x2*x2+x3*x3);
        s4 += __shfl_xor(s4, 16); s4 += __shfl_xor(s4, 32);
        q4 += __shfl_xor(q4, 16); q4 += __shfl_xor(q4, 32);
        float mx = fmaxf(fmaxf(x0,x1), fmaxf(x2,x3));
        float mn = fminf(fminf(x0,x1), fminf(x2,x3));
        mx = fmaxf(mx, __shfl_xor(mx, 16)); mx = fmaxf(mx, __shfl_xor(mx, 32));
        mn = fminf(mn, __shfl_xor(mn, 16)); mn = fminf(mn, __shfl_xor(mn, 32));
        if (lg == 0) {
          sred[w][c][0] = s4; sred[w][c][1] = q4;
          smm[w][c][0] = mx; smm[w][c][1] = mn;
        }
      }
      __syncthreads();
      if (t < 256) {
        float ps = (sred[0][t][0]+sred[1][t][0])+(sred[2][t][0]+sred[3][t][0]);
        float pq = (sred[0][t][1]+sred[1][t][1])+(sred[2][t][1]+sred[3][t][1]);
        psum[(size_t)t*NBLK + blk] = ps;
        psq [(size_t)t*NBLK + blk] = pq;
#pragma unroll
        for (int gi2 = 0; gi2 < 2; ++gi2) {
          float mx = fmaxf(smm[gi2*2][t][0], smm[gi2*2+1][t][0]);
          float mn = fminf(smm[gi2*2][t][1], smm[gi2*2+1][t][1]);
          size_t o = ((size_t)(b*256 + t))*SS + (pr*2 + gi2);
          maxb[o] = mx; minb[o] = mn;
        }
      }
    }
  }
}

// ---------- 5. finalize BN stats -> affine a,b (optional bias fold) ----------
__global__ __launch_bounds__(256) void bnstats_finalize_kernel(
    const float* __restrict__ psum, const float* __restrict__ psq,
    const float* __restrict__ gamma, const float* __restrict__ beta,
    const float* __restrict__ bias, int fold,
    float* __restrict__ aa, float* __restrict__ bb)
{
  int c = blockIdx.x, t = threadIdx.x;
  double s = 0.0, q = 0.0;
  for (int i = t; i < NBLK; i += 256) {
    s += (double)psum[(size_t)c*NBLK + i];
    q += (double)psq [(size_t)c*NBLK + i];
  }
#pragma unroll
  for (int m = 1; m <= 32; m <<= 1) { s += __shfl_xor(s, m); q += __shfl_xor(q, m); }
  __shared__ double sd[4][2];
  if ((t & 63) == 0) { sd[t>>6][0] = s; sd[t>>6][1] = q; }
  __syncthreads();
  if (t == 0) {
    double S = (sd[0][0]+sd[1][0])+(sd[2][0]+sd[3][0]);
    double Q = (sd[0][1]+sd[1][1])+(sd[2][1]+sd[3][1]);
    double mean = S / (double)MTOT;
    double var  = Q / (double)MTOT - mean*mean;
    double rs = 1.0 / sqrt(var + 1e-5);
    double a = (double)gamma[c] * rs;
    aa[c] = (float)a;
    double bbv = (double)beta[c] - mean * a;
    if (fold) bbv += a * (double)bias[c];
    bb[c] = (float)bbv;
  }
}

// ---------- 6. final output ----------
__global__ __launch_bounds__(256) void final_out_kernel(
    const float* __restrict__ aa, const float* __restrict__ bb,
    const float* __restrict__ maxb, const float* __restrict__ minb,
    float* __restrict__ out2)
{
  int blk = blockIdx.x;            // b*256 + c
  int c = blk & 255;
  float a = aa[c], bo = bb[c];
  const float* src = (a >= 0.f) ? maxb : minb;
  size_t base = (size_t)blk * SS;
  for (int s = threadIdx.x; s < SS; s += 256)
    out2[base + s] = fmaxf(fmaf(a, src[base + s], bo), 0.f);
}

// ---------- launch ----------
extern "C" void kernel_launch(void* const* d_in, const int* in_sizes, int n_in,
                              void* d_out, int out_size, void* d_ws, size_t ws_size,
                              hipStream_t stream) {
  const float* xyz    = (const float*)d_in[0];
  const float* points = (const float*)d_in[1];
  const float* W0 = (const float*)d_in[2];
  const float* b0 = (const float*)d_in[3];
  const float* g0 = (const float*)d_in[4];
  const float* be0= (const float*)d_in[5];
  const float* W1 = (const float*)d_in[6];
  const float* b1 = (const float*)d_in[7];
  const float* g1 = (const float*)d_in[8];
  const float* be1= (const float*)d_in[9];
  const float* W2 = (const float*)d_in[10];
  const float* b2 = (const float*)d_in[11];
  const float* g2 = (const float*)d_in[12];
  const float* be2= (const float*)d_in[13];

  float* out = (float*)d_out;
  float* newxyz = out;                 // (8,1024,3)
  float* out2   = out + BB*SS*3;       // (8,256,1024)

  char* ws = (char*)d_ws;
  int*      nn   = (int*)ws;
  ushort_t* wb1  = (ushort_t*)(ws + 0x100000);
  ushort_t* wb2  = (ushort_t*)(ws + 0x106000);
  ushort_t* wb3  = (ushort_t*)(ws + 0x10E000);
  float* aa1 = (float*)(ws + 0x11E000);
  float* bb1 = aa1 + 128;
  float* aa2 = bb1 + 128;
  float* bb2 = aa2 + 128;
  float* aa3 = bb2 + 128;
  float* bb3 = aa3 + 256;
  float* psum1 = (float*)(ws + 0x120000);
  float* psq1  = (float*)(ws + 0x320000);
  float* psum2 = (float*)(ws + 0x520000);
  float* psq2  = (float*)(ws + 0x720000);
  float* psum3 = (float*)(ws + 0x920000);
  float* psq3  = (float*)(ws + 0xD20000);
  float* maxb  = (float*)(ws + 0x1120000);
  float* minb  = (float*)(ws + 0x1920000);
  ushort_t* z  = (ushort_t*)(ws + 0x2120000);     // 64 MB f16 activations
  const size_t NEEDED = 0x6120000ull;

  prep_kernel<<<64, 256, 0, stream>>>(W0, W1, W2, wb1, wb2, wb3);
  fps_kernel<<<BB, 128, 0, stream>>>(xyz, newxyz);
  knn_kernel<<<BB*SS, 256, 0, stream>>>(xyz, newxyz, nn);

  if (ws_size >= NEEDED) {
    conv1_kernel<<<NBLK, 256, 0, stream>>>(xyz, points, newxyz, nn, wb1, b0,
                                           z, psum1, psq1);
    bnstats_finalize_kernel<<<O1, 256, 0, stream>>>(psum1, psq1, g0, be0, b0, 1, aa1, bb1);
    conv2_kernel<<<NBLK, 256, 0, stream>>>(z, wb2, b1, aa1, bb1, psum2, psq2);
    bnstats_finalize_kernel<<<O2, 256, 0, stream>>>(psum2, psq2, g1, be1, b1, 1, aa2, bb2);
    conv3_kernel<<<NBLK, 256, 0, stream>>>(z, wb3, b2, aa2, bb2, psum3, psq3, maxb, minb);
    bnstats_finalize_kernel<<<O3, 256, 0, stream>>>(psum3, psq3, g2, be2, b2, 0, aa3, bb3);
  } else {
    fused_kernel<1><<<NBLK, 256, 0, stream>>>(xyz, points, newxyz, nn, wb1, wb2, wb3,
        b0, b1, b2, aa1, bb1, aa2, bb2, psum1, psq1, maxb, minb);
    bnstats_finalize_kernel<<<O1, 256, 0, stream>>>(psum1, psq1, g0, be0, b0, 0, aa1, bb1);
    fused_kernel<2><<<NBLK, 256, 0, stream>>>(xyz, points, newxyz, nn, wb1, wb2, wb3,
        b0, b1, b2, aa1, bb1, aa2, bb2, psum2, psq2, maxb, minb);
    bnstats_finalize_kernel<<<O2, 256, 0, stream>>>(psum2, psq2, g1, be1, b1, 0, aa2, bb2);
    fused_kernel<3><<<NBLK, 256, 0, stream>>>(xyz, points, newxyz, nn, wb1, wb2, wb3,
        b0, b1, b2, aa1, bb1, aa2, bb2, psum3, psq3, maxb, minb);
    bnstats_finalize_kernel<<<O3, 256, 0, stream>>>(psum3, psq3, g2, be2, b2, 0, aa3, bb3);
  }

  final_out_kernel<<<BB*O3, 256, 0, stream>>>(aa3, bb3, maxb, minb, out2);
}

// Round 8
// 1563.330 us; speedup vs baseline: 1.1484x; 1.1148x over previous
//
#include <hip/hip_runtime.h>
#include <cstdint>
#include <cstddef>

typedef _Float16 half8 __attribute__((ext_vector_type(8)));
typedef float f32x4 __attribute__((ext_vector_type(4)));
typedef unsigned short ushort_t;

// ---------- constants ----------
#define BB 8
#define NN 4096
#define CIN 64
#define SS 1024
#define KK 32
#define O1 128
#define O2 128
#define O3 256
#define C0 67          // 3 + CIN
#define P0 104         // LDS pitch for feat0 (odd multiple of 8 halves = 16B)
#define P1 136         // LDS pitch for activations (odd multiple of 8 halves)
#define MTOT (BB*SS*KK)   // 262144 rows
#define NBLK 4096         // fused grid: B * S/2

// ---------- helpers ----------
__device__ __forceinline__ ushort_t f2h(float v) {
  union { _Float16 h; ushort_t u; } cv;
  cv.h = (_Float16)v;
  return cv.u;
}
__device__ __forceinline__ half8 ldv(const ushort_t* p) {
  return *(const half8*)p;
}
__device__ __forceinline__ f32x4 MF(half8 a, half8 b, f32x4 c) {
  return __builtin_amdgcn_mfma_f32_16x16x32_f16(a, b, c, 0, 0, 0);
}

// ---- DPP-only 64-lane (value, idx) reduce; result lands in LANE 63.
// MAXM=true: argmax (ties -> smaller idx). MAXM=false: argmin (ties -> smaller idx).
template<bool MAXM>
__device__ __forceinline__ void wave_red_dpp(float& d, int& i) {
#define RED_TAKE(d2, i2) \
  { bool take = MAXM ? ((d2) > d || ((d2) == d && (i2) < i)) \
                     : ((d2) < d || ((d2) == d && (i2) < i)); \
    if (take) { d = (d2); i = (i2); } }
#define RED_DPP(CTRL) \
  { float d2_ = __int_as_float(__builtin_amdgcn_update_dpp(0, __float_as_int(d), CTRL, 0xf, 0xf, true)); \
    int   i2_ = __builtin_amdgcn_update_dpp(0, i, CTRL, 0xf, 0xf, true); \
    RED_TAKE(d2_, i2_) }
  RED_DPP(0x128)   // row_ror:8
  RED_DPP(0x124)   // row_ror:4
  RED_DPP(0x122)   // row_ror:2
  RED_DPP(0x121)   // row_ror:1
  RED_DPP(0x142)   // row_bcast:15
  RED_DPP(0x143)   // row_bcast:31
#undef RED_DPP
#undef RED_TAKE
}

// ---------- 1. FPS: one block (256 thr, 4 waves) per batch ----------
__global__ __launch_bounds__(256, 1) void fps_kernel(const float* __restrict__ xyz,
                                                     float* __restrict__ newxyz) {
  int b = blockIdx.x, t = threadIdx.x;
  __shared__ float sxyz[NN*3];
  __shared__ float snew[SS*3];                    // centroid buffer
  __shared__ __align__(16) float wpair[2][4][2];  // [parity][wave][{dist, idx-bits}]
  {
    const float4* src = (const float4*)(xyz + (size_t)b * (NN*3));
    float4* dst = (float4*)sxyz;
    for (int i = t; i < NN*3/4; i += 256) dst[i] = src[i];
  }
  __syncthreads();
  float px[16], py[16], pz[16], dist[16];
#pragma unroll
  for (int j = 0; j < 16; ++j) {
    int n = t + 256*j;
    px[j] = sxyz[n*3+0]; py[j] = sxyz[n*3+1]; pz[j] = sxyz[n*3+2];
    dist[j] = 1e10f;
  }
  float cx = sxyz[0], cy = sxyz[1], cz = sxyz[2];
  for (int s = 0; s < SS; ++s) {
    if (t == 0) {
      snew[s*3+0] = cx; snew[s*3+1] = cy; snew[s*3+2] = cz;
    }
    // distance + 4 independent argmax chains (dep depth 4)
    float bd0 = -1.f, bd1 = -1.f, bd2 = -1.f, bd3 = -1.f;
    int   bi0 = 0, bi1 = 0, bi2 = 0, bi3 = 0;
#pragma unroll
    for (int j = 0; j < 16; ++j) {
      // exact np order: ((dx*dx + dy*dy) + dz*dz), no FMA contraction
      float dx = __fadd_rn(px[j], -cx);
      float dy = __fadd_rn(py[j], -cy);
      float dz = __fadd_rn(pz[j], -cz);
      float d = __fadd_rn(__fadd_rn(__fmul_rn(dx,dx), __fmul_rn(dy,dy)), __fmul_rn(dz,dz));
      float nd = fminf(dist[j], d);
      dist[j] = nd;
      int idx = t + 256*j;
      // within a chain j increases -> strict > keeps first (smallest) index on tie
      if ((j & 3) == 0) { if (nd > bd0) { bd0 = nd; bi0 = idx; } }
      if ((j & 3) == 1) { if (nd > bd1) { bd1 = nd; bi1 = idx; } }
      if ((j & 3) == 2) { if (nd > bd2) { bd2 = nd; bi2 = idx; } }
      if ((j & 3) == 3) { if (nd > bd3) { bd3 = nd; bi3 = idx; } }
    }
    // combine chains, tie-break by smaller index (np.argmax = first max)
    float bd = bd0; int bi = bi0;
    if (bd1 > bd || (bd1 == bd && bi1 < bi)) { bd = bd1; bi = bi1; }
    if (bd2 > bd || (bd2 == bd && bi2 < bi)) { bd = bd2; bi = bi2; }
    if (bd3 > bd || (bd3 == bd && bi3 < bi)) { bd = bd3; bi = bi3; }

    wave_red_dpp<true>(bd, bi);     // result in lane 63

    int p = s & 1;
    if ((t & 63) == 63) {
      wpair[p][t>>6][0] = bd;
      ((int*)&wpair[p][t>>6][0])[1] = bi;
    }
    __syncthreads();
    // packed read of all 4 (dist,idx) partials: 2x float4
    float4 q0 = *(const float4*)&wpair[p][0][0];
    float4 q1 = *(const float4*)&wpair[p][2][0];
    float fd = q0.x; int fi = __float_as_int(q0.y);
#define CMB(dv, iv) { float od = (dv); int oi = __float_as_int(iv); \
      if (od > fd || (od == fd && oi < fi)) { fd = od; fi = oi; } }
    CMB(q0.z, q0.w) CMB(q1.x, q1.y) CMB(q1.z, q1.w)
#undef CMB
    cx = sxyz[fi*3+0]; cy = sxyz[fi*3+1]; cz = sxyz[fi*3+2];
  }
  __syncthreads();
  { // coalesced write-out of all centroids
    float4* dst = (float4*)(newxyz + (size_t)b * (SS*3));
    const float4* src = (const float4*)snew;
    for (int i = t; i < SS*3/4; i += 256) dst[i] = src[i];
  }
}

// ---------- 2. KNN: one block per query, extract-min 32x with local-min cache ----------
__global__ __launch_bounds__(256) void knn_kernel(const float* __restrict__ xyz,
                                                  const float* __restrict__ newxyz,
                                                  int* __restrict__ nn) {
  int blk = blockIdx.x;           // b*1024 + s
  int b = blk >> 10;
  int t = threadIdx.x;
  __shared__ __align__(16) float lpair[2][4][2];  // [parity][wave][{dist, idx-bits}]
  __shared__ int sidx[KK];                        // extracted indices (no in-loop global store)
  float qx = newxyz[(size_t)blk*3+0];
  float qy = newxyz[(size_t)blk*3+1];
  float qz = newxyz[(size_t)blk*3+2];
  float cs = __fadd_rn(__fadd_rn(__fmul_rn(qx,qx), __fmul_rn(qy,qy)), __fmul_rn(qz,qz));
  const float* base = xyz + (size_t)b * (NN*3);
  float d[16];
#pragma unroll
  for (int j = 0; j < 16; ++j) {
    int n = t + 256*j;
    float px = base[n*3+0], py = base[n*3+1], pz = base[n*3+2];
    float xs  = __fadd_rn(__fadd_rn(__fmul_rn(px,px), __fmul_rn(py,py)), __fmul_rn(pz,pz));
    float dot = __fadd_rn(__fadd_rn(__fmul_rn(qx,px), __fmul_rn(qy,py)), __fmul_rn(qz,pz));
    // reference: (cs - 2*dot) + xs
    d[j] = __fadd_rn(__fadd_rn(cs, -__fmul_rn(2.f, dot)), xs);
  }
  // cached per-thread local min (lexicographic (dist, idx))
  float lmin = 3.0e38f; int lidx = 0x7fffffff;
#pragma unroll
  for (int j = 0; j < 16; ++j) {
    if (d[j] < lmin) { lmin = d[j]; lidx = t + 256*j; }   // strict < keeps smaller idx
  }
  for (int it = 0; it < KK; ++it) {
    float bd = lmin; int bi = lidx;
    wave_red_dpp<false>(bd, bi);    // result in lane 63
    int p = it & 1;
    if ((t & 63) == 63) {
      lpair[p][t>>6][0] = bd;
      ((int*)&lpair[p][t>>6][0])[1] = bi;
    }
    __syncthreads();
    float4 q0 = *(const float4*)&lpair[p][0][0];
    float4 q1 = *(const float4*)&lpair[p][2][0];
    float fd = q0.x; int fi = __float_as_int(q0.y);
#define CMB(dv, iv) { float od = (dv); int oi = __float_as_int(iv); \
      if (od < fd || (od == fd && oi < fi)) { fd = od; fi = oi; } }
    CMB(q0.z, q0.w) CMB(q1.x, q1.y) CMB(q1.z, q1.w)
#undef CMB
    if (t == 0) sidx[it] = fi;
    // only the owner thread invalidates its slot and rescans its 16 candidates
    if ((fi & 255) == t) {
      int jj = fi >> 8;
#pragma unroll
      for (int j = 0; j < 16; ++j) if (j == jj) d[j] = 3.0e38f;
      lmin = 3.0e38f; lidx = 0x7fffffff;
#pragma unroll
      for (int j = 0; j < 16; ++j) {
        if (d[j] < lmin) { lmin = d[j]; lidx = t + 256*j; }
      }
    }
  }
  __syncthreads();
  if (t < KK) nn[(size_t)blk*KK + t] = sidx[t];
}

// ---------- 3. weights fp32 -> fp16, zero-padded ----------
__global__ void prep_kernel(const float* __restrict__ W0, const float* __restrict__ W1,
                            const float* __restrict__ W2,
                            ushort_t* __restrict__ wb1, ushort_t* __restrict__ wb2,
                            ushort_t* __restrict__ wb3) {
  int i = blockIdx.x*256 + threadIdx.x;
  int stride = gridDim.x*256;
  const int n1 = O1*96, n2 = O2*128, n3 = O3*128;
  for (; i < n1+n2+n3; i += stride) {
    if (i < n1) {
      int o = i / 96, k = i - o*96;
      wb1[i] = (k < C0) ? f2h(W0[o*C0 + k]) : (ushort_t)0;
    } else if (i < n1+n2) {
      int j = i - n1;
      wb2[j] = f2h(W1[j]);
    } else {
      int j = i - n1 - n2;
      wb3[j] = f2h(W2[j]);
    }
  }
}

// ---------- shared epilogue helper (fallback path) ----------
template<int NT>
__device__ __forceinline__ void stats_and_store(
    const f32x4* acc, const float* __restrict__ bias,
    float (*sred)[256][2],
    int w, int lr, int lg, int t, int blk,
    float* __restrict__ psum, float* __restrict__ psq)
{
#pragma unroll
  for (int n = 0; n < NT; ++n) {
    int c = n*16 + lr;
    float bi = bias[c];
    float x0 = acc[n][0]+bi, x1 = acc[n][1]+bi, x2 = acc[n][2]+bi, x3 = acc[n][3]+bi;
    float s4 = (x0+x1)+(x2+x3);
    float q4 = (x0*x0+x1*x1)+(x2*x2+x3*x3);
    s4 += __shfl_xor(s4, 16); s4 += __shfl_xor(s4, 32);
    q4 += __shfl_xor(q4, 16); q4 += __shfl_xor(q4, 32);
    if (lg == 0) { sred[w][c][0] = s4; sred[w][c][1] = q4; }
  }
  __syncthreads();
  if (t < NT*16) {
    float ps = (sred[0][t][0]+sred[1][t][0])+(sred[2][t][0]+sred[3][t][0]);
    float pq = (sred[0][t][1]+sred[1][t][1])+(sred[2][t][1]+sred[3][t][1]);
    psum[(size_t)t*NBLK + blk] = ps;
    psq [(size_t)t*NBLK + blk] = pq;
  }
}

// ---------- feat0 staging (shared by conv1 + fallback) ----------
__device__ __forceinline__ void stage_feat0(
    const float* __restrict__ xyz, const float* __restrict__ points,
    const float* __restrict__ newxyz, const int* __restrict__ nn,
    ushort_t* sF, int t, int b, int pr)
{
  int r = t >> 2, q = t & 3;
  int gi = r >> 5, j = r & 31;
  int bs = (b << 10) + (pr*2 + gi);
  int idx = nn[(size_t)bs*KK + j];
  const float* prow = points + ((size_t)(b*NN + idx))*CIN;
  const float* pxyz = xyz    + ((size_t)(b*NN + idx))*3;
  const float* ctr  = newxyz + (size_t)bs*3;
  ushort_t* dst = &sF[r*P0];
  if (q < 3) dst[q] = f2h(pxyz[q] - ctr[q]);
#pragma unroll
  for (int ii = 0; ii < 4; ++ii) {
    float4 v = *(const float4*)&prow[q*4 + ii*16];
    int c = 3 + q*4 + ii*16;
    dst[c+0] = f2h(v.x); dst[c+1] = f2h(v.y); dst[c+2] = f2h(v.z); dst[c+3] = f2h(v.w);
  }
  for (int c = C0 + q; c < P0; c += 4) dst[c] = 0;
}

// ---------- 4a. conv1 (materialized): feat0 -> conv1 -> z + stats1 ----------
__global__ __launch_bounds__(256) void conv1_kernel(
    const float* __restrict__ xyz, const float* __restrict__ points,
    const float* __restrict__ newxyz, const int* __restrict__ nn,
    const ushort_t* __restrict__ wb1, const float* __restrict__ bias1,
    ushort_t* __restrict__ z, float* __restrict__ psum, float* __restrict__ psq)
{
  __shared__ __align__(16) ushort_t sF[64*P0];
  __shared__ __align__(16) ushort_t s1[64*P1];
  __shared__ float sred[4][O1][2];
  int t = threadIdx.x, blk = blockIdx.x;
  int b = blk >> 9, pr = blk & 511;

  stage_feat0(xyz, points, newxyz, nn, sF, t, b, pr);
  __syncthreads();

  int w = t >> 6, l = t & 63;
  int lr = l & 15, lg = l >> 4;
  int ko = lg * 8;
  int arow = w*16 + lr;

  half8 a0 = ldv(&sF[arow*P0 +  0 + ko]);
  half8 a1 = ldv(&sF[arow*P0 + 32 + ko]);
  half8 a2 = ldv(&sF[arow*P0 + 64 + ko]);
  f32x4 acc1[8];
#pragma unroll
  for (int n = 0; n < 8; ++n) {
    const ushort_t* wrow = wb1 + (size_t)(n*16 + lr)*96 + ko;
    f32x4 c = {0.f,0.f,0.f,0.f};
    c = MF(a0, ldv(wrow +  0), c);
    c = MF(a1, ldv(wrow + 32), c);
    c = MF(a2, ldv(wrow + 64), c);
    acc1[n] = c;
  }

  // epilogue: raw acc -> s1 (for coalesced z store), stats on acc+bias
#pragma unroll
  for (int n = 0; n < 8; ++n) {
    int c = n*16 + lr;
#pragma unroll
    for (int rr = 0; rr < 4; ++rr)
      s1[(w*16 + lg*4 + rr)*P1 + c] = f2h(acc1[n][rr]);
    float bi = bias1[c];
    float x0 = acc1[n][0]+bi, x1 = acc1[n][1]+bi, x2 = acc1[n][2]+bi, x3 = acc1[n][3]+bi;
    float s4 = (x0+x1)+(x2+x3);
    float q4 = (x0*x0+x1*x1)+(x2*x2+x3*x3);
    s4 += __shfl_xor(s4, 16); s4 += __shfl_xor(s4, 32);
    q4 += __shfl_xor(q4, 16); q4 += __shfl_xor(q4, 32);
    if (lg == 0) { sred[w][c][0] = s4; sred[w][c][1] = q4; }
  }
  __syncthreads();
  { // coalesced z store: 64 rows x 128 halves
    size_t chunk = (size_t)blk * (64*128);
#pragma unroll
    for (int i = 0; i < 4; ++i) {
      int off = t*8 + i*2048;
      *(half8*)&z[chunk + off] = ldv(&s1[(off>>7)*P1 + (off&127)]);
    }
  }
  if (t < O1) {
    float ps = (sred[0][t][0]+sred[1][t][0])+(sred[2][t][0]+sred[3][t][0]);
    float pq = (sred[0][t][1]+sred[1][t][1])+(sred[2][t][1]+sred[3][t][1]);
    psum[(size_t)t*NBLK + blk] = ps;
    psq [(size_t)t*NBLK + blk] = pq;
  }
}

// ---------- 4b. conv2 (materialized): z -> affine1+relu -> conv2 -> z + stats2 ----------
__global__ __launch_bounds__(256) void conv2_kernel(
    ushort_t* __restrict__ z, const ushort_t* __restrict__ wb2,
    const float* __restrict__ bias2,
    const float* __restrict__ aa1, const float* __restrict__ bb1,
    float* __restrict__ psum, float* __restrict__ psq)
{
  __shared__ __align__(16) ushort_t s1[64*P1];
  __shared__ float sred[4][O2][2];
  int t = threadIdx.x, blk = blockIdx.x;
  size_t chunk = (size_t)blk * (64*128);

  int c0 = (t*8) & 127;
  float av[8], bv[8];
  {
    float4 alo = *(const float4*)&aa1[c0], ahi = *(const float4*)&aa1[c0+4];
    float4 blo = *(const float4*)&bb1[c0], bhi = *(const float4*)&bb1[c0+4];
    av[0]=alo.x; av[1]=alo.y; av[2]=alo.z; av[3]=alo.w;
    av[4]=ahi.x; av[5]=ahi.y; av[6]=ahi.z; av[7]=ahi.w;
    bv[0]=blo.x; bv[1]=blo.y; bv[2]=blo.z; bv[3]=blo.w;
    bv[4]=bhi.x; bv[5]=bhi.y; bv[6]=bhi.z; bv[7]=bhi.w;
  }
#pragma unroll
  for (int i = 0; i < 4; ++i) {
    int off = t*8 + i*2048;
    half8 v = ldv(&z[chunk + off]);
    half8 y;
#pragma unroll
    for (int jj = 0; jj < 8; ++jj)
      y[jj] = (_Float16)fmaxf(av[jj]*(float)v[jj] + bv[jj], 0.f);
    *(half8*)&s1[(off>>7)*P1 + c0] = y;
  }
  __syncthreads();

  int w = t >> 6, l = t & 63;
  int lr = l & 15, lg = l >> 4;
  int ko = lg * 8;
  int arow = w*16 + lr;

  half8 f0 = ldv(&s1[arow*P1 +  0 + ko]);
  half8 f1 = ldv(&s1[arow*P1 + 32 + ko]);
  half8 f2 = ldv(&s1[arow*P1 + 64 + ko]);
  half8 f3 = ldv(&s1[arow*P1 + 96 + ko]);
  f32x4 acc2[8];
#pragma unroll
  for (int n = 0; n < 8; ++n) {
    const ushort_t* wrow = wb2 + (size_t)(n*16 + lr)*128 + ko;
    f32x4 c = {0.f,0.f,0.f,0.f};
    c = MF(f0, ldv(wrow +  0), c);
    c = MF(f1, ldv(wrow + 32), c);
    c = MF(f2, ldv(wrow + 64), c);
    c = MF(f3, ldv(wrow + 96), c);
    acc2[n] = c;
  }
  __syncthreads();   // all s1 frag reads done before overwrite

#pragma unroll
  for (int n = 0; n < 8; ++n) {
    int c = n*16 + lr;
#pragma unroll
    for (int rr = 0; rr < 4; ++rr)
      s1[(w*16 + lg*4 + rr)*P1 + c] = f2h(acc2[n][rr]);
    float bi = bias2[c];
    float x0 = acc2[n][0]+bi, x1 = acc2[n][1]+bi, x2 = acc2[n][2]+bi, x3 = acc2[n][3]+bi;
    float s4 = (x0+x1)+(x2+x3);
    float q4 = (x0*x0+x1*x1)+(x2*x2+x3*x3);
    s4 += __shfl_xor(s4, 16); s4 += __shfl_xor(s4, 32);
    q4 += __shfl_xor(q4, 16); q4 += __shfl_xor(q4, 32);
    if (lg == 0) { sred[w][c][0] = s4; sred[w][c][1] = q4; }
  }
  __syncthreads();
#pragma unroll
  for (int i = 0; i < 4; ++i) {
    int off = t*8 + i*2048;
    *(half8*)&z[chunk + off] = ldv(&s1[(off>>7)*P1 + (off&127)]);
  }
  if (t < O2) {
    float ps = (sred[0][t][0]+sred[1][t][0])+(sred[2][t][0]+sred[3][t][0]);
    float pq = (sred[0][t][1]+sred[1][t][1])+(sred[2][t][1]+sred[3][t][1]);
    psum[(size_t)t*NBLK + blk] = ps;
    psq [(size_t)t*NBLK + blk] = pq;
  }
}

// ---------- 4c. conv3 (materialized): z -> affine2+relu -> conv3 -> stats3 + max/min ----------
__global__ __launch_bounds__(256) void conv3_kernel(
    const ushort_t* __restrict__ z, const ushort_t* __restrict__ wb3,
    const float* __restrict__ bias3,
    const float* __restrict__ aa2, const float* __restrict__ bb2,
    float* __restrict__ psum, float* __restrict__ psq,
    float* __restrict__ maxb, float* __restrict__ minb)
{
  __shared__ __align__(16) ushort_t s2[64*P1];
  __shared__ float sred[4][O3][2];
  __shared__ float smm[4][O3][2];
  int t = threadIdx.x, blk = blockIdx.x;
  int b = blk >> 9, pr = blk & 511;
  size_t chunk = (size_t)blk * (64*128);

  int c0 = (t*8) & 127;
  float av[8], bv[8];
  {
    float4 alo = *(const float4*)&aa2[c0], ahi = *(const float4*)&aa2[c0+4];
    float4 blo = *(const float4*)&bb2[c0], bhi = *(const float4*)&bb2[c0+4];
    av[0]=alo.x; av[1]=alo.y; av[2]=alo.z; av[3]=alo.w;
    av[4]=ahi.x; av[5]=ahi.y; av[6]=ahi.z; av[7]=ahi.w;
    bv[0]=blo.x; bv[1]=blo.y; bv[2]=blo.z; bv[3]=blo.w;
    bv[4]=bhi.x; bv[5]=bhi.y; bv[6]=bhi.z; bv[7]=bhi.w;
  }
#pragma unroll
  for (int i = 0; i < 4; ++i) {
    int off = t*8 + i*2048;
    half8 v = ldv(&z[chunk + off]);
    half8 y;
#pragma unroll
    for (int jj = 0; jj < 8; ++jj)
      y[jj] = (_Float16)fmaxf(av[jj]*(float)v[jj] + bv[jj], 0.f);
    *(half8*)&s2[(off>>7)*P1 + c0] = y;
  }
  __syncthreads();

  int w = t >> 6, l = t & 63;
  int lr = l & 15, lg = l >> 4;
  int ko = lg * 8;
  int arow = w*16 + lr;

  half8 g0 = ldv(&s2[arow*P1 +  0 + ko]);
  half8 g1 = ldv(&s2[arow*P1 + 32 + ko]);
  half8 g2 = ldv(&s2[arow*P1 + 64 + ko]);
  half8 g3 = ldv(&s2[arow*P1 + 96 + ko]);
  f32x4 acc3[16];
#pragma unroll
  for (int n = 0; n < 16; ++n) {
    const ushort_t* wrow = wb3 + (size_t)(n*16 + lr)*128 + ko;
    f32x4 c = {0.f,0.f,0.f,0.f};
    c = MF(g0, ldv(wrow +  0), c);
    c = MF(g1, ldv(wrow + 32), c);
    c = MF(g2, ldv(wrow + 64), c);
    c = MF(g3, ldv(wrow + 96), c);
    acc3[n] = c;
  }

#pragma unroll
  for (int n = 0; n < 16; ++n) {
    int c = n*16 + lr;
    float bi = bias3[c];
    float x0 = acc3[n][0]+bi, x1 = acc3[n][1]+bi, x2 = acc3[n][2]+bi, x3 = acc3[n][3]+bi;
    float s4 = (x0+x1)+(x2+x3);
    float q4 = (x0*x0+x1*x1)+(x2*x2+x3*x3);
    s4 += __shfl_xor(s4, 16); s4 += __shfl_xor(s4, 32);
    q4 += __shfl_xor(q4, 16); q4 += __shfl_xor(q4, 32);
    float mx = fmaxf(fmaxf(x0,x1), fmaxf(x2,x3));
    float mn = fminf(fminf(x0,x1), fminf(x2,x3));
    mx = fmaxf(mx, __shfl_xor(mx, 16)); mx = fmaxf(mx, __shfl_xor(mx, 32));
    mn = fminf(mn, __shfl_xor(mn, 16)); mn = fminf(mn, __shfl_xor(mn, 32));
    if (lg == 0) {
      sred[w][c][0] = s4; sred[w][c][1] = q4;
      smm[w][c][0] = mx; smm[w][c][1] = mn;
    }
  }
  __syncthreads();
  if (t < 256) {
    float ps = (sred[0][t][0]+sred[1][t][0])+(sred[2][t][0]+sred[3][t][0]);
    float pq = (sred[0][t][1]+sred[1][t][1])+(sred[2][t][1]+sred[3][t][1]);
    psum[(size_t)t*NBLK + blk] = ps;
    psq [(size_t)t*NBLK + blk] = pq;
#pragma unroll
    for (int gi2 = 0; gi2 < 2; ++gi2) {
      float mx = fmaxf(smm[gi2*2][t][0], smm[gi2*2+1][t][0]);
      float mn = fminf(smm[gi2*2][t][1], smm[gi2*2+1][t][1]);
      size_t o = ((size_t)(b*256 + t))*SS + (pr*2 + gi2);
      maxb[o] = mx; minb[o] = mn;
    }
  }
}

// ---------- 4-fallback. fused conv chain (recompute prefix) ----------
template<int DEPTH>
__global__ __launch_bounds__(256) void fused_kernel(
    const float* __restrict__ xyz, const float* __restrict__ points,
    const float* __restrict__ newxyz, const int* __restrict__ nn,
    const ushort_t* __restrict__ wb1, const ushort_t* __restrict__ wb2,
    const ushort_t* __restrict__ wb3,
    const float* __restrict__ bias1, const float* __restrict__ bias2,
    const float* __restrict__ bias3,
    const float* __restrict__ aa1, const float* __restrict__ bb1,
    const float* __restrict__ aa2, const float* __restrict__ bb2,
    float* __restrict__ psum, float* __restrict__ psq,
    float* __restrict__ maxb, float* __restrict__ minb)
{
  __shared__ __align__(16) ushort_t sF[64*P0];
  __shared__ __align__(16) ushort_t s1[(DEPTH>=2) ? 64*P1 : 8];
  __shared__ __align__(16) ushort_t s2[(DEPTH>=3) ? 64*P1 : 8];
  __shared__ float sred[4][256][2];
  __shared__ float smm[(DEPTH>=3)?4:1][256][2];

  int t = threadIdx.x, blk = blockIdx.x;
  int b = blk >> 9, pr = blk & 511;

  stage_feat0(xyz, points, newxyz, nn, sF, t, b, pr);
  __syncthreads();

  int w = t >> 6, l = t & 63;
  int lr = l & 15, lg = l >> 4;
  int ko = lg * 8;
  int arow = w*16 + lr;

  half8 a0 = ldv(&sF[arow*P0 +  0 + ko]);
  half8 a1 = ldv(&sF[arow*P0 + 32 + ko]);
  half8 a2 = ldv(&sF[arow*P0 + 64 + ko]);
  f32x4 acc1[8];
#pragma unroll
  for (int n = 0; n < 8; ++n) {
    const ushort_t* wrow = wb1 + (size_t)(n*16 + lr)*96 + ko;
    f32x4 c = {0.f,0.f,0.f,0.f};
    c = MF(a0, ldv(wrow +  0), c);
    c = MF(a1, ldv(wrow + 32), c);
    c = MF(a2, ldv(wrow + 64), c);
    acc1[n] = c;
  }

  if constexpr (DEPTH == 1) {
    stats_and_store<8>(acc1, bias1, sred, w, lr, lg, t, blk, psum, psq);
  } else {
#pragma unroll
    for (int n = 0; n < 8; ++n) {
      int c = n*16 + lr;
      float a = aa1[c], bo = bb1[c], bi = bias1[c];
#pragma unroll
      for (int rr = 0; rr < 4; ++rr) {
        float y = fmaxf(a*(acc1[n][rr] + bi) + bo, 0.f);
        s1[(w*16 + lg*4 + rr)*P1 + c] = f2h(y);
      }
    }
    __syncthreads();

    half8 f0 = ldv(&s1[arow*P1 +  0 + ko]);
    half8 f1 = ldv(&s1[arow*P1 + 32 + ko]);
    half8 f2 = ldv(&s1[arow*P1 + 64 + ko]);
    half8 f3 = ldv(&s1[arow*P1 + 96 + ko]);
    f32x4 acc2[8];
#pragma unroll
    for (int n = 0; n < 8; ++n) {
      const ushort_t* wrow = wb2 + (size_t)(n*16 + lr)*128 + ko;
      f32x4 c = {0.f,0.f,0.f,0.f};
      c = MF(f0, ldv(wrow +  0), c);
      c = MF(f1, ldv(wrow + 32), c);
      c = MF(f2, ldv(wrow + 64), c);
      c = MF(f3, ldv(wrow + 96), c);
      acc2[n] = c;
    }

    if constexpr (DEPTH == 2) {
      stats_and_store<8>(acc2, bias2, sred, w, lr, lg, t, blk, psum, psq);
    } else {
#pragma unroll
      for (int n = 0; n < 8; ++n) {
        int c = n*16 + lr;
        float a = aa2[c], bo = bb2[c], bi = bias2[c];
#pragma unroll
        for (int rr = 0; rr < 4; ++rr) {
          float y = fmaxf(a*(acc2[n][rr] + bi) + bo, 0.f);
          s2[(w*16 + lg*4 + rr)*P1 + c] = f2h(y);
        }
      }
      __syncthreads();

      half8 g0 = ldv(&s2[arow*P1 +  0 + ko]);
      half8 g1 = ldv(&s2[arow*P1 + 32 + ko]);
      half8 g2 = ldv(&s2[arow*P1 + 64 + ko]);
      half8 g3 = ldv(&s2[arow*P1 + 96 + ko]);
      f32x4 acc3[16];
#pragma unroll
      for (int n = 0; n < 16; ++n) {
        const ushort_t* wrow = wb3 + (size_t)(n*16 + lr)*128 + ko;
        f32x4 c = {0.f,0.f,0.f,0.f};
        c = MF(g0, ldv(wrow +  0), c);
        c = MF(g1, ldv(wrow + 32), c);
        c = MF(g2, ldv(wrow + 64), c);
        c = MF(g3, ldv(wrow + 96), c);
        acc3[n] = c;
      }

#pragma unroll
      for (int n = 0; n < 16; ++n) {
        int c = n*16 + lr;
        float bi = bias3[c];
        float x0 = acc3[n][0]+bi, x1 = acc3[n][1]+bi, x2 = acc3[n][2]+bi, x3 = acc3[n][3]+bi;
        float s4 = (x0+x1)+(x2+x3);
        float q4 = (x0*x0+x1*x1)+(x2*x2+x3*x3);
        s4 += __shfl_xor(s4, 16); s4 += __shfl_xor(s4, 32);
        q4 += __shfl_xor(q4, 16); q4 += __shfl_xor(q4, 32);
        float mx = fmaxf(fmaxf(x0,x1), fmaxf(x2,x3));
        float mn = fminf(fminf(x0,x1), fminf(x2,x3));
        mx = fmaxf(mx, __shfl_xor(mx, 16)); mx = fmaxf(mx, __shfl_xor(mx, 32));
        mn = fminf(mn, __shfl_xor(mn, 16)); mn = fminf(mn, __shfl_xor(mn, 32));
        if (lg == 0) {
          sred[w][c][0] = s4; sred[w][c][1] = q4;
          smm[w][c][0] = mx; smm[w][c][1] = mn;
        }
      }
      __syncthreads();
      if (t < 256) {
        float ps = (sred[0][t][0]+sred[1][t][0])+(sred[2][t][0]+sred[3][t][0]);
        float pq = (sred[0][t][1]+sred[1][t][1])+(sred[2][t][1]+sred[3][t][1]);
        psum[(size_t)t*NBLK + blk] = ps;
        psq [(size_t)t*NBLK + blk] = pq;
#pragma unroll
        for (int gi2 = 0; gi2 < 2; ++gi2) {
          float mx = fmaxf(smm[gi2*2][t][0], smm[gi2*2+1][t][0]);
          float mn = fminf(smm[gi2*2][t][1], smm[gi2*2+1][t][1]);
          size_t o = ((size_t)(b*256 + t))*SS + (pr*2 + gi2);
          maxb[o] = mx; minb[o] = mn;
        }
      }
    }
  }
}

// ---------- 5. finalize BN stats -> affine a,b (optional bias fold) ----------
__global__ __launch_bounds__(256) void bnstats_finalize_kernel(
    const float* __restrict__ psum, const float* __restrict__ psq,
    const float* __restrict__ gamma, const float* __restrict__ beta,
    const float* __restrict__ bias, int fold,
    float* __restrict__ aa, float* __restrict__ bb)
{
  int c = blockIdx.x, t = threadIdx.x;
  double s = 0.0, q = 0.0;
  for (int i = t; i < NBLK; i += 256) {
    s += (double)psum[(size_t)c*NBLK + i];
    q += (double)psq [(size_t)c*NBLK + i];
  }
#pragma unroll
  for (int m = 1; m <= 32; m <<= 1) { s += __shfl_xor(s, m); q += __shfl_xor(q, m); }
  __shared__ double sd[4][2];
  if ((t & 63) == 0) { sd[t>>6][0] = s; sd[t>>6][1] = q; }
  __syncthreads();
  if (t == 0) {
    double S = (sd[0][0]+sd[1][0])+(sd[2][0]+sd[3][0]);
    double Q = (sd[0][1]+sd[1][1])+(sd[2][1]+sd[3][1]);
    double mean = S / (double)MTOT;
    double var  = Q / (double)MTOT - mean*mean;
    double rs = 1.0 / sqrt(var + 1e-5);
    double a = (double)gamma[c] * rs;
    aa[c] = (float)a;
    double bbv = (double)beta[c] - mean * a;
    if (fold) bbv += a * (double)bias[c];
    bb[c] = (float)bbv;
  }
}

// ---------- 6. final output ----------
__global__ __launch_bounds__(256) void final_out_kernel(
    const float* __restrict__ aa, const float* __restrict__ bb,
    const float* __restrict__ maxb, const float* __restrict__ minb,
    float* __restrict__ out2)
{
  int blk = blockIdx.x;            // b*256 + c
  int c = blk & 255;
  float a = aa[c], bo = bb[c];
  const float* src = (a >= 0.f) ? maxb : minb;
  size_t base = (size_t)blk * SS;
  for (int s = threadIdx.x; s < SS; s += 256)
    out2[base + s] = fmaxf(fmaf(a, src[base + s], bo), 0.f);
}

// ---------- launch ----------
extern "C" void kernel_launch(void* const* d_in, const int* in_sizes, int n_in,
                              void* d_out, int out_size, void* d_ws, size_t ws_size,
                              hipStream_t stream) {
  const float* xyz    = (const float*)d_in[0];
  const float* points = (const float*)d_in[1];
  const float* W0 = (const float*)d_in[2];
  const float* b0 = (const float*)d_in[3];
  const float* g0 = (const float*)d_in[4];
  const float* be0= (const float*)d_in[5];
  const float* W1 = (const float*)d_in[6];
  const float* b1 = (const float*)d_in[7];
  const float* g1 = (const float*)d_in[8];
  const float* be1= (const float*)d_in[9];
  const float* W2 = (const float*)d_in[10];
  const float* b2 = (const float*)d_in[11];
  const float* g2 = (const float*)d_in[12];
  const float* be2= (const float*)d_in[13];

  float* out = (float*)d_out;
  float* newxyz = out;                 // (8,1024,3)
  float* out2   = out + BB*SS*3;       // (8,256,1024)

  char* ws = (char*)d_ws;
  int*      nn   = (int*)ws;
  ushort_t* wb1  = (ushort_t*)(ws + 0x100000);
  ushort_t* wb2  = (ushort_t*)(ws + 0x106000);
  ushort_t* wb3  = (ushort_t*)(ws + 0x10E000);
  float* aa1 = (float*)(ws + 0x11E000);
  float* bb1 = aa1 + 128;
  float* aa2 = bb1 + 128;
  float* bb2 = aa2 + 128;
  float* aa3 = bb2 + 128;
  float* bb3 = aa3 + 256;
  float* psum1 = (float*)(ws + 0x120000);
  float* psq1  = (float*)(ws + 0x320000);
  float* psum2 = (float*)(ws + 0x520000);
  float* psq2  = (float*)(ws + 0x720000);
  float* psum3 = (float*)(ws + 0x920000);
  float* psq3  = (float*)(ws + 0xD20000);
  float* maxb  = (float*)(ws + 0x1120000);
  float* minb  = (float*)(ws + 0x1920000);
  ushort_t* z  = (ushort_t*)(ws + 0x2120000);     // 64 MB f16 activations
  const size_t NEEDED = 0x6120000ull;

  prep_kernel<<<64, 256, 0, stream>>>(W0, W1, W2, wb1, wb2, wb3);
  fps_kernel<<<BB, 256, 0, stream>>>(xyz, newxyz);
  knn_kernel<<<BB*SS, 256, 0, stream>>>(xyz, newxyz, nn);

  if (ws_size >= NEEDED) {
    conv1_kernel<<<NBLK, 256, 0, stream>>>(xyz, points, newxyz, nn, wb1, b0,
                                           z, psum1, psq1);
    bnstats_finalize_kernel<<<O1, 256, 0, stream>>>(psum1, psq1, g0, be0, b0, 1, aa1, bb1);
    conv2_kernel<<<NBLK, 256, 0, stream>>>(z, wb2, b1, aa1, bb1, psum2, psq2);
    bnstats_finalize_kernel<<<O2, 256, 0, stream>>>(psum2, psq2, g1, be1, b1, 1, aa2, bb2);
    conv3_kernel<<<NBLK, 256, 0, stream>>>(z, wb3, b2, aa2, bb2, psum3, psq3, maxb, minb);
    bnstats_finalize_kernel<<<O3, 256, 0, stream>>>(psum3, psq3, g2, be2, b2, 0, aa3, bb3);
  } else {
    fused_kernel<1><<<NBLK, 256, 0, stream>>>(xyz, points, newxyz, nn, wb1, wb2, wb3,
        b0, b1, b2, aa1, bb1, aa2, bb2, psum1, psq1, maxb, minb);
    bnstats_finalize_kernel<<<O1, 256, 0, stream>>>(psum1, psq1, g0, be0, b0, 0, aa1, bb1);
    fused_kernel<2><<<NBLK, 256, 0, stream>>>(xyz, points, newxyz, nn, wb1, wb2, wb3,
        b0, b1, b2, aa1, bb1, aa2, bb2, psum2, psq2, maxb, minb);
    bnstats_finalize_kernel<<<O2, 256, 0, stream>>>(psum2, psq2, g1, be1, b1, 0, aa2, bb2);
    fused_kernel<3><<<NBLK, 256, 0, stream>>>(xyz, points, newxyz, nn, wb1, wb2, wb3,
        b0, b1, b2, aa1, bb1, aa2, bb2, psum3, psq3, maxb, minb);
    bnstats_finalize_kernel<<<O3, 256, 0, stream>>>(psum3, psq3, g2, be2, b2, 0, aa3, bb3);
  }

  final_out_kernel<<<BB*O3, 256, 0, stream>>>(aa3, bb3, maxb, minb, out2);
}

// Round 9
// 1546.525 us; speedup vs baseline: 1.1609x; 1.0109x over previous
//
#include <hip/hip_runtime.h>
#include <cstdint>
#include <cstddef>

typedef _Float16 half8 __attribute__((ext_vector_type(8)));
typedef float f32x4 __attribute__((ext_vector_type(4)));
typedef float f32x2 __attribute__((ext_vector_type(2)));
typedef unsigned short ushort_t;

// ---------- constants ----------
#define BB 8
#define NN 4096
#define CIN 64
#define SS 1024
#define KK 32
#define O1 128
#define O2 128
#define O3 256
#define C0 67          // 3 + CIN
#define P0 104         // LDS pitch for feat0 (odd multiple of 8 halves = 16B)
#define P1 136         // LDS pitch for activations (odd multiple of 8 halves)
#define MTOT (BB*SS*KK)   // 262144 rows
#define NBLK 4096         // fused grid: B * S/2

// ---------- helpers ----------
__device__ __forceinline__ ushort_t f2h(float v) {
  union { _Float16 h; ushort_t u; } cv;
  cv.h = (_Float16)v;
  return cv.u;
}
__device__ __forceinline__ half8 ldv(const ushort_t* p) {
  return *(const half8*)p;
}
__device__ __forceinline__ f32x4 MF(half8 a, half8 b, f32x4 c) {
  return __builtin_amdgcn_mfma_f32_16x16x32_f16(a, b, c, 0, 0, 0);
}

// ---- DPP-only 64-lane (value, idx) reduce; result lands in LANE 63.
// MAXM=true: argmax (ties -> smaller idx). MAXM=false: argmin (ties -> smaller idx).
template<bool MAXM>
__device__ __forceinline__ void wave_red_dpp(float& d, int& i) {
#define RED_TAKE(d2, i2) \
  { bool take = MAXM ? ((d2) > d || ((d2) == d && (i2) < i)) \
                     : ((d2) < d || ((d2) == d && (i2) < i)); \
    if (take) { d = (d2); i = (i2); } }
#define RED_DPP(CTRL) \
  { float d2_ = __int_as_float(__builtin_amdgcn_update_dpp(0, __float_as_int(d), CTRL, 0xf, 0xf, true)); \
    int   i2_ = __builtin_amdgcn_update_dpp(0, i, CTRL, 0xf, 0xf, true); \
    RED_TAKE(d2_, i2_) }
  RED_DPP(0x128)   // row_ror:8
  RED_DPP(0x124)   // row_ror:4
  RED_DPP(0x122)   // row_ror:2
  RED_DPP(0x121)   // row_ror:1
  RED_DPP(0x142)   // row_bcast:15
  RED_DPP(0x143)   // row_bcast:31
#undef RED_DPP
#undef RED_TAKE
}

// ---------- 1. FPS: one block (256 thr, 4 waves) per batch ----------
// Distance math on f32x2 pairs -> v_pk_add_f32 / v_pk_mul_f32 (packed FP32).
// #pragma clang fp contract(off) preserves the reference's exact rounding
// order ((dx*dx + dy*dy) + dz*dz) with no FMA fusion -> bit-identical to np.
__global__ __launch_bounds__(256, 1) void fps_kernel(const float* __restrict__ xyz,
                                                     float* __restrict__ newxyz) {
  int b = blockIdx.x, t = threadIdx.x;
  __shared__ float sxyz[NN*3];
  __shared__ float snew[SS*3];                    // centroid buffer
  __shared__ __align__(16) float wpair[2][4][2];  // [parity][wave][{dist, idx-bits}]
  {
    const float4* src = (const float4*)(xyz + (size_t)b * (NN*3));
    float4* dst = (float4*)sxyz;
    for (int i = t; i < NN*3/4; i += 256) dst[i] = src[i];
  }
  __syncthreads();
  // pair layout: pair j holds point-block indices (2j, 2j+1), i.e. global
  // idx (t + 512j, t + 512j + 256)
  f32x2 px2[8], py2[8], pz2[8], d2[8];
#pragma unroll
  for (int j = 0; j < 8; ++j) {
    int n0 = t + 512*j, n1 = n0 + 256;
    f32x2 vx = {sxyz[n0*3+0], sxyz[n1*3+0]};
    f32x2 vy = {sxyz[n0*3+1], sxyz[n1*3+1]};
    f32x2 vz = {sxyz[n0*3+2], sxyz[n1*3+2]};
    px2[j] = vx; py2[j] = vy; pz2[j] = vz;
    f32x2 ini = {1e10f, 1e10f};
    d2[j] = ini;
  }
  float cx = sxyz[0], cy = sxyz[1], cz = sxyz[2];
  for (int s = 0; s < SS; ++s) {
    if (t == 0) {
      snew[s*3+0] = cx; snew[s*3+1] = cy; snew[s*3+2] = cz;
    }
    // distance (packed) + 4 independent argmax chains (dep depth 4)
    float bd0 = -1.f, bd1 = -1.f, bd2 = -1.f, bd3 = -1.f;
    int   bi0 = 0, bi1 = 0, bi2 = 0, bi3 = 0;
    {
#pragma clang fp contract(off)
      f32x2 c2x = {cx, cx}, c2y = {cy, cy}, c2z = {cz, cz};
#pragma unroll
      for (int j = 0; j < 8; ++j) {
        f32x2 dx = px2[j] - c2x;
        f32x2 dy = py2[j] - c2y;
        f32x2 dz = pz2[j] - c2z;
        f32x2 dd = (dx*dx + dy*dy) + dz*dz;   // exact np order, no contraction
        float nd0 = fminf(d2[j][0], dd[0]);
        float nd1 = fminf(d2[j][1], dd[1]);
        d2[j][0] = nd0; d2[j][1] = nd1;
        int i0 = t + 512*j, i1 = i0 + 256;
        // chains ascend in idx -> strict > keeps first (smallest) idx on tie
        if ((j & 1) == 0) {
          if (nd0 > bd0) { bd0 = nd0; bi0 = i0; }
          if (nd1 > bd1) { bd1 = nd1; bi1 = i1; }
        } else {
          if (nd0 > bd2) { bd2 = nd0; bi2 = i0; }
          if (nd1 > bd3) { bd3 = nd1; bi3 = i1; }
        }
      }
    }
    // combine chains, tie-break by smaller index (np.argmax = first max)
    float bd = bd0; int bi = bi0;
    if (bd1 > bd || (bd1 == bd && bi1 < bi)) { bd = bd1; bi = bi1; }
    if (bd2 > bd || (bd2 == bd && bi2 < bi)) { bd = bd2; bi = bi2; }
    if (bd3 > bd || (bd3 == bd && bi3 < bi)) { bd = bd3; bi = bi3; }

    wave_red_dpp<true>(bd, bi);     // result in lane 63

    int p = s & 1;
    if ((t & 63) == 63) {
      wpair[p][t>>6][0] = bd;
      ((int*)&wpair[p][t>>6][0])[1] = bi;
    }
    __syncthreads();
    // packed read of all 4 (dist,idx) partials: 2x float4
    float4 q0 = *(const float4*)&wpair[p][0][0];
    float4 q1 = *(const float4*)&wpair[p][2][0];
    float fd = q0.x; int fi = __float_as_int(q0.y);
#define CMB(dv, iv) { float od = (dv); int oi = __float_as_int(iv); \
      if (od > fd || (od == fd && oi < fi)) { fd = od; fi = oi; } }
    CMB(q0.z, q0.w) CMB(q1.x, q1.y) CMB(q1.z, q1.w)
#undef CMB
    cx = sxyz[fi*3+0]; cy = sxyz[fi*3+1]; cz = sxyz[fi*3+2];
  }
  __syncthreads();
  { // coalesced write-out of all centroids
    float4* dst = (float4*)(newxyz + (size_t)b * (SS*3));
    const float4* src = (const float4*)snew;
    for (int i = t; i < SS*3/4; i += 256) dst[i] = src[i];
  }
}

// ---------- 2. KNN: one block per query, extract-min 32x with local-min cache ----------
__global__ __launch_bounds__(256) void knn_kernel(const float* __restrict__ xyz,
                                                  const float* __restrict__ newxyz,
                                                  int* __restrict__ nn) {
  int blk = blockIdx.x;           // b*1024 + s
  int b = blk >> 10;
  int t = threadIdx.x;
  __shared__ __align__(16) float lpair[2][4][2];  // [parity][wave][{dist, idx-bits}]
  __shared__ int sidx[KK];                        // extracted indices (no in-loop global store)
  float qx = newxyz[(size_t)blk*3+0];
  float qy = newxyz[(size_t)blk*3+1];
  float qz = newxyz[(size_t)blk*3+2];
  float cs = __fadd_rn(__fadd_rn(__fmul_rn(qx,qx), __fmul_rn(qy,qy)), __fmul_rn(qz,qz));
  const float* base = xyz + (size_t)b * (NN*3);
  float d[16];
#pragma unroll
  for (int j = 0; j < 16; ++j) {
    int n = t + 256*j;
    float px = base[n*3+0], py = base[n*3+1], pz = base[n*3+2];
    float xs  = __fadd_rn(__fadd_rn(__fmul_rn(px,px), __fmul_rn(py,py)), __fmul_rn(pz,pz));
    float dot = __fadd_rn(__fadd_rn(__fmul_rn(qx,px), __fmul_rn(qy,py)), __fmul_rn(qz,pz));
    // reference: (cs - 2*dot) + xs
    d[j] = __fadd_rn(__fadd_rn(cs, -__fmul_rn(2.f, dot)), xs);
  }
  // cached per-thread local min (lexicographic (dist, idx))
  float lmin = 3.0e38f; int lidx = 0x7fffffff;
#pragma unroll
  for (int j = 0; j < 16; ++j) {
    if (d[j] < lmin) { lmin = d[j]; lidx = t + 256*j; }   // strict < keeps smaller idx
  }
  for (int it = 0; it < KK; ++it) {
    float bd = lmin; int bi = lidx;
    wave_red_dpp<false>(bd, bi);    // result in lane 63
    int p = it & 1;
    if ((t & 63) == 63) {
      lpair[p][t>>6][0] = bd;
      ((int*)&lpair[p][t>>6][0])[1] = bi;
    }
    __syncthreads();
    float4 q0 = *(const float4*)&lpair[p][0][0];
    float4 q1 = *(const float4*)&lpair[p][2][0];
    float fd = q0.x; int fi = __float_as_int(q0.y);
#define CMB(dv, iv) { float od = (dv); int oi = __float_as_int(iv); \
      if (od < fd || (od == fd && oi < fi)) { fd = od; fi = oi; } }
    CMB(q0.z, q0.w) CMB(q1.x, q1.y) CMB(q1.z, q1.w)
#undef CMB
    if (t == 0) sidx[it] = fi;
    // only the owner thread invalidates its slot and rescans its 16 candidates
    if ((fi & 255) == t) {
      int jj = fi >> 8;
#pragma unroll
      for (int j = 0; j < 16; ++j) if (j == jj) d[j] = 3.0e38f;
      lmin = 3.0e38f; lidx = 0x7fffffff;
#pragma unroll
      for (int j = 0; j < 16; ++j) {
        if (d[j] < lmin) { lmin = d[j]; lidx = t + 256*j; }
      }
    }
  }
  __syncthreads();
  if (t < KK) nn[(size_t)blk*KK + t] = sidx[t];
}

// ---------- 3. weights fp32 -> fp16, zero-padded ----------
__global__ void prep_kernel(const float* __restrict__ W0, const float* __restrict__ W1,
                            const float* __restrict__ W2,
                            ushort_t* __restrict__ wb1, ushort_t* __restrict__ wb2,
                            ushort_t* __restrict__ wb3) {
  int i = blockIdx.x*256 + threadIdx.x;
  int stride = gridDim.x*256;
  const int n1 = O1*96, n2 = O2*128, n3 = O3*128;
  for (; i < n1+n2+n3; i += stride) {
    if (i < n1) {
      int o = i / 96, k = i - o*96;
      wb1[i] = (k < C0) ? f2h(W0[o*C0 + k]) : (ushort_t)0;
    } else if (i < n1+n2) {
      int j = i - n1;
      wb2[j] = f2h(W1[j]);
    } else {
      int j = i - n1 - n2;
      wb3[j] = f2h(W2[j]);
    }
  }
}

// ---------- shared epilogue helper (fallback path) ----------
template<int NT>
__device__ __forceinline__ void stats_and_store(
    const f32x4* acc, const float* __restrict__ bias,
    float (*sred)[256][2],
    int w, int lr, int lg, int t, int blk,
    float* __restrict__ psum, float* __restrict__ psq)
{
#pragma unroll
  for (int n = 0; n < NT; ++n) {
    int c = n*16 + lr;
    float bi = bias[c];
    float x0 = acc[n][0]+bi, x1 = acc[n][1]+bi, x2 = acc[n][2]+bi, x3 = acc[n][3]+bi;
    float s4 = (x0+x1)+(x2+x3);
    float q4 = (x0*x0+x1*x1)+(x2*x2+x3*x3);
    s4 += __shfl_xor(s4, 16); s4 += __shfl_xor(s4, 32);
    q4 += __shfl_xor(q4, 16); q4 += __shfl_xor(q4, 32);
    if (lg == 0) { sred[w][c][0] = s4; sred[w][c][1] = q4; }
  }
  __syncthreads();
  if (t < NT*16) {
    float ps = (sred[0][t][0]+sred[1][t][0])+(sred[2][t][0]+sred[3][t][0]);
    float pq = (sred[0][t][1]+sred[1][t][1])+(sred[2][t][1]+sred[3][t][1]);
    psum[(size_t)t*NBLK + blk] = ps;
    psq [(size_t)t*NBLK + blk] = pq;
  }
}

// ---------- feat0 staging (shared by conv1 + fallback) ----------
__device__ __forceinline__ void stage_feat0(
    const float* __restrict__ xyz, const float* __restrict__ points,
    const float* __restrict__ newxyz, const int* __restrict__ nn,
    ushort_t* sF, int t, int b, int pr)
{
  int r = t >> 2, q = t & 3;
  int gi = r >> 5, j = r & 31;
  int bs = (b << 10) + (pr*2 + gi);
  int idx = nn[(size_t)bs*KK + j];
  const float* prow = points + ((size_t)(b*NN + idx))*CIN;
  const float* pxyz = xyz    + ((size_t)(b*NN + idx))*3;
  const float* ctr  = newxyz + (size_t)bs*3;
  ushort_t* dst = &sF[r*P0];
  if (q < 3) dst[q] = f2h(pxyz[q] - ctr[q]);
#pragma unroll
  for (int ii = 0; ii < 4; ++ii) {
    float4 v = *(const float4*)&prow[q*4 + ii*16];
    int c = 3 + q*4 + ii*16;
    dst[c+0] = f2h(v.x); dst[c+1] = f2h(v.y); dst[c+2] = f2h(v.z); dst[c+3] = f2h(v.w);
  }
  for (int c = C0 + q; c < P0; c += 4) dst[c] = 0;
}

// ---------- 4a. conv1 (materialized): feat0 -> conv1 -> z + stats1 ----------
__global__ __launch_bounds__(256) void conv1_kernel(
    const float* __restrict__ xyz, const float* __restrict__ points,
    const float* __restrict__ newxyz, const int* __restrict__ nn,
    const ushort_t* __restrict__ wb1, const float* __restrict__ bias1,
    ushort_t* __restrict__ z, float* __restrict__ psum, float* __restrict__ psq)
{
  __shared__ __align__(16) ushort_t sF[64*P0];
  __shared__ __align__(16) ushort_t s1[64*P1];
  __shared__ float sred[4][O1][2];
  int t = threadIdx.x, blk = blockIdx.x;
  int b = blk >> 9, pr = blk & 511;

  stage_feat0(xyz, points, newxyz, nn, sF, t, b, pr);
  __syncthreads();

  int w = t >> 6, l = t & 63;
  int lr = l & 15, lg = l >> 4;
  int ko = lg * 8;
  int arow = w*16 + lr;

  half8 a0 = ldv(&sF[arow*P0 +  0 + ko]);
  half8 a1 = ldv(&sF[arow*P0 + 32 + ko]);
  half8 a2 = ldv(&sF[arow*P0 + 64 + ko]);
  f32x4 acc1[8];
#pragma unroll
  for (int n = 0; n < 8; ++n) {
    const ushort_t* wrow = wb1 + (size_t)(n*16 + lr)*96 + ko;
    f32x4 c = {0.f,0.f,0.f,0.f};
    c = MF(a0, ldv(wrow +  0), c);
    c = MF(a1, ldv(wrow + 32), c);
    c = MF(a2, ldv(wrow + 64), c);
    acc1[n] = c;
  }

  // epilogue: raw acc -> s1 (for coalesced z store), stats on acc+bias
#pragma unroll
  for (int n = 0; n < 8; ++n) {
    int c = n*16 + lr;
#pragma unroll
    for (int rr = 0; rr < 4; ++rr)
      s1[(w*16 + lg*4 + rr)*P1 + c] = f2h(acc1[n][rr]);
    float bi = bias1[c];
    float x0 = acc1[n][0]+bi, x1 = acc1[n][1]+bi, x2 = acc1[n][2]+bi, x3 = acc1[n][3]+bi;
    float s4 = (x0+x1)+(x2+x3);
    float q4 = (x0*x0+x1*x1)+(x2*x2+x3*x3);
    s4 += __shfl_xor(s4, 16); s4 += __shfl_xor(s4, 32);
    q4 += __shfl_xor(q4, 16); q4 += __shfl_xor(q4, 32);
    if (lg == 0) { sred[w][c][0] = s4; sred[w][c][1] = q4; }
  }
  __syncthreads();
  { // coalesced z store: 64 rows x 128 halves
    size_t chunk = (size_t)blk * (64*128);
#pragma unroll
    for (int i = 0; i < 4; ++i) {
      int off = t*8 + i*2048;
      *(half8*)&z[chunk + off] = ldv(&s1[(off>>7)*P1 + (off&127)]);
    }
  }
  if (t < O1) {
    float ps = (sred[0][t][0]+sred[1][t][0])+(sred[2][t][0]+sred[3][t][0]);
    float pq = (sred[0][t][1]+sred[1][t][1])+(sred[2][t][1]+sred[3][t][1]);
    psum[(size_t)t*NBLK + blk] = ps;
    psq [(size_t)t*NBLK + blk] = pq;
  }
}

// ---------- 4b. conv2 (materialized): z -> affine1+relu -> conv2 -> z + stats2 ----------
__global__ __launch_bounds__(256) void conv2_kernel(
    ushort_t* __restrict__ z, const ushort_t* __restrict__ wb2,
    const float* __restrict__ bias2,
    const float* __restrict__ aa1, const float* __restrict__ bb1,
    float* __restrict__ psum, float* __restrict__ psq)
{
  __shared__ __align__(16) ushort_t s1[64*P1];
  __shared__ float sred[4][O2][2];
  int t = threadIdx.x, blk = blockIdx.x;
  size_t chunk = (size_t)blk * (64*128);

  int c0 = (t*8) & 127;
  float av[8], bv[8];
  {
    float4 alo = *(const float4*)&aa1[c0], ahi = *(const float4*)&aa1[c0+4];
    float4 blo = *(const float4*)&bb1[c0], bhi = *(const float4*)&bb1[c0+4];
    av[0]=alo.x; av[1]=alo.y; av[2]=alo.z; av[3]=alo.w;
    av[4]=ahi.x; av[5]=ahi.y; av[6]=ahi.z; av[7]=ahi.w;
    bv[0]=blo.x; bv[1]=blo.y; bv[2]=blo.z; bv[3]=blo.w;
    bv[4]=bhi.x; bv[5]=bhi.y; bv[6]=bhi.z; bv[7]=bhi.w;
  }
#pragma unroll
  for (int i = 0; i < 4; ++i) {
    int off = t*8 + i*2048;
    half8 v = ldv(&z[chunk + off]);
    half8 y;
#pragma unroll
    for (int jj = 0; jj < 8; ++jj)
      y[jj] = (_Float16)fmaxf(av[jj]*(float)v[jj] + bv[jj], 0.f);
    *(half8*)&s1[(off>>7)*P1 + c0] = y;
  }
  __syncthreads();

  int w = t >> 6, l = t & 63;
  int lr = l & 15, lg = l >> 4;
  int ko = lg * 8;
  int arow = w*16 + lr;

  half8 f0 = ldv(&s1[arow*P1 +  0 + ko]);
  half8 f1 = ldv(&s1[arow*P1 + 32 + ko]);
  half8 f2 = ldv(&s1[arow*P1 + 64 + ko]);
  half8 f3 = ldv(&s1[arow*P1 + 96 + ko]);
  f32x4 acc2[8];
#pragma unroll
  for (int n = 0; n < 8; ++n) {
    const ushort_t* wrow = wb2 + (size_t)(n*16 + lr)*128 + ko;
    f32x4 c = {0.f,0.f,0.f,0.f};
    c = MF(f0, ldv(wrow +  0), c);
    c = MF(f1, ldv(wrow + 32), c);
    c = MF(f2, ldv(wrow + 64), c);
    c = MF(f3, ldv(wrow + 96), c);
    acc2[n] = c;
  }
  __syncthreads();   // all s1 frag reads done before overwrite

#pragma unroll
  for (int n = 0; n < 8; ++n) {
    int c = n*16 + lr;
#pragma unroll
    for (int rr = 0; rr < 4; ++rr)
      s1[(w*16 + lg*4 + rr)*P1 + c] = f2h(acc2[n][rr]);
    float bi = bias2[c];
    float x0 = acc2[n][0]+bi, x1 = acc2[n][1]+bi, x2 = acc2[n][2]+bi, x3 = acc2[n][3]+bi;
    float s4 = (x0+x1)+(x2+x3);
    float q4 = (x0*x0+x1*x1)+(x2*x2+x3*x3);
    s4 += __shfl_xor(s4, 16); s4 += __shfl_xor(s4, 32);
    q4 += __shfl_xor(q4, 16); q4 += __shfl_xor(q4, 32);
    if (lg == 0) { sred[w][c][0] = s4; sred[w][c][1] = q4; }
  }
  __syncthreads();
#pragma unroll
  for (int i = 0; i < 4; ++i) {
    int off = t*8 + i*2048;
    *(half8*)&z[chunk + off] = ldv(&s1[(off>>7)*P1 + (off&127)]);
  }
  if (t < O2) {
    float ps = (sred[0][t][0]+sred[1][t][0])+(sred[2][t][0]+sred[3][t][0]);
    float pq = (sred[0][t][1]+sred[1][t][1])+(sred[2][t][1]+sred[3][t][1]);
    psum[(size_t)t*NBLK + blk] = ps;
    psq [(size_t)t*NBLK + blk] = pq;
  }
}

// ---------- 4c. conv3 (materialized): z -> affine2+relu -> conv3 -> stats3 + max/min ----------
__global__ __launch_bounds__(256) void conv3_kernel(
    const ushort_t* __restrict__ z, const ushort_t* __restrict__ wb3,
    const float* __restrict__ bias3,
    const float* __restrict__ aa2, const float* __restrict__ bb2,
    float* __restrict__ psum, float* __restrict__ psq,
    float* __restrict__ maxb, float* __restrict__ minb)
{
  __shared__ __align__(16) ushort_t s2[64*P1];
  __shared__ float sred[4][O3][2];
  __shared__ float smm[4][O3][2];
  int t = threadIdx.x, blk = blockIdx.x;
  int b = blk >> 9, pr = blk & 511;
  size_t chunk = (size_t)blk * (64*128);

  int c0 = (t*8) & 127;
  float av[8], bv[8];
  {
    float4 alo = *(const float4*)&aa2[c0], ahi = *(const float4*)&aa2[c0+4];
    float4 blo = *(const float4*)&bb2[c0], bhi = *(const float4*)&bb2[c0+4];
    av[0]=alo.x; av[1]=alo.y; av[2]=alo.z; av[3]=alo.w;
    av[4]=ahi.x; av[5]=ahi.y; av[6]=ahi.z; av[7]=ahi.w;
    bv[0]=blo.x; bv[1]=blo.y; bv[2]=blo.z; bv[3]=blo.w;
    bv[4]=bhi.x; bv[5]=bhi.y; bv[6]=bhi.z; bv[7]=bhi.w;
  }
#pragma unroll
  for (int i = 0; i < 4; ++i) {
    int off = t*8 + i*2048;
    half8 v = ldv(&z[chunk + off]);
    half8 y;
#pragma unroll
    for (int jj = 0; jj < 8; ++jj)
      y[jj] = (_Float16)fmaxf(av[jj]*(float)v[jj] + bv[jj], 0.f);
    *(half8*)&s2[(off>>7)*P1 + c0] = y;
  }
  __syncthreads();

  int w = t >> 6, l = t & 63;
  int lr = l & 15, lg = l >> 4;
  int ko = lg * 8;
  int arow = w*16 + lr;

  half8 g0 = ldv(&s2[arow*P1 +  0 + ko]);
  half8 g1 = ldv(&s2[arow*P1 + 32 + ko]);
  half8 g2 = ldv(&s2[arow*P1 + 64 + ko]);
  half8 g3 = ldv(&s2[arow*P1 + 96 + ko]);
  f32x4 acc3[16];
#pragma unroll
  for (int n = 0; n < 16; ++n) {
    const ushort_t* wrow = wb3 + (size_t)(n*16 + lr)*128 + ko;
    f32x4 c = {0.f,0.f,0.f,0.f};
    c = MF(g0, ldv(wrow +  0), c);
    c = MF(g1, ldv(wrow + 32), c);
    c = MF(g2, ldv(wrow + 64), c);
    c = MF(g3, ldv(wrow + 96), c);
    acc3[n] = c;
  }

#pragma unroll
  for (int n = 0; n < 16; ++n) {
    int c = n*16 + lr;
    float bi = bias3[c];
    float x0 = acc3[n][0]+bi, x1 = acc3[n][1]+bi, x2 = acc3[n][2]+bi, x3 = acc3[n][3]+bi;
    float s4 = (x0+x1)+(x2+x3);
    float q4 = (x0*x0+x1*x1)+(x2*x2+x3*x3);
    s4 += __shfl_xor(s4, 16); s4 += __shfl_xor(s4, 32);
    q4 += __shfl_xor(q4, 16); q4 += __shfl_xor(q4, 32);
    float mx = fmaxf(fmaxf(x0,x1), fmaxf(x2,x3));
    float mn = fminf(fminf(x0,x1), fminf(x2,x3));
    mx = fmaxf(mx, __shfl_xor(mx, 16)); mx = fmaxf(mx, __shfl_xor(mx, 32));
    mn = fminf(mn, __shfl_xor(mn, 16)); mn = fminf(mn, __shfl_xor(mn, 32));
    if (lg == 0) {
      sred[w][c][0] = s4; sred[w][c][1] = q4;
      smm[w][c][0] = mx; smm[w][c][1] = mn;
    }
  }
  __syncthreads();
  if (t < 256) {
    float ps = (sred[0][t][0]+sred[1][t][0])+(sred[2][t][0]+sred[3][t][0]);
    float pq = (sred[0][t][1]+sred[1][t][1])+(sred[2][t][1]+sred[3][t][1]);
    psum[(size_t)t*NBLK + blk] = ps;
    psq [(size_t)t*NBLK + blk] = pq;
#pragma unroll
    for (int gi2 = 0; gi2 < 2; ++gi2) {
      float mx = fmaxf(smm[gi2*2][t][0], smm[gi2*2+1][t][0]);
      float mn = fminf(smm[gi2*2][t][1], smm[gi2*2+1][t][1]);
      size_t o = ((size_t)(b*256 + t))*SS + (pr*2 + gi2);
      maxb[o] = mx; minb[o] = mn;
    }
  }
}

// ---------- 4-fallback. fused conv chain (recompute prefix) ----------
template<int DEPTH>
__global__ __launch_bounds__(256) void fused_kernel(
    const float* __restrict__ xyz, const float* __restrict__ points,
    const float* __restrict__ newxyz, const int* __restrict__ nn,
    const ushort_t* __restrict__ wb1, const ushort_t* __restrict__ wb2,
    const ushort_t* __restrict__ wb3,
    const float* __restrict__ bias1, const float* __restrict__ bias2,
    const float* __restrict__ bias3,
    const float* __restrict__ aa1, const float* __restrict__ bb1,
    const float* __restrict__ aa2, const float* __restrict__ bb2,
    float* __restrict__ psum, float* __restrict__ psq,
    float* __restrict__ maxb, float* __restrict__ minb)
{
  __shared__ __align__(16) ushort_t sF[64*P0];
  __shared__ __align__(16) ushort_t s1[(DEPTH>=2) ? 64*P1 : 8];
  __shared__ __align__(16) ushort_t s2[(DEPTH>=3) ? 64*P1 : 8];
  __shared__ float sred[4][256][2];
  __shared__ float smm[(DEPTH>=3)?4:1][256][2];

  int t = threadIdx.x, blk = blockIdx.x;
  int b = blk >> 9, pr = blk & 511;

  stage_feat0(xyz, points, newxyz, nn, sF, t, b, pr);
  __syncthreads();

  int w = t >> 6, l = t & 63;
  int lr = l & 15, lg = l >> 4;
  int ko = lg * 8;
  int arow = w*16 + lr;

  half8 a0 = ldv(&sF[arow*P0 +  0 + ko]);
  half8 a1 = ldv(&sF[arow*P0 + 32 + ko]);
  half8 a2 = ldv(&sF[arow*P0 + 64 + ko]);
  f32x4 acc1[8];
#pragma unroll
  for (int n = 0; n < 8; ++n) {
    const ushort_t* wrow = wb1 + (size_t)(n*16 + lr)*96 + ko;
    f32x4 c = {0.f,0.f,0.f,0.f};
    c = MF(a0, ldv(wrow +  0), c);
    c = MF(a1, ldv(wrow + 32), c);
    c = MF(a2, ldv(wrow + 64), c);
    acc1[n] = c;
  }

  if constexpr (DEPTH == 1) {
    stats_and_store<8>(acc1, bias1, sred, w, lr, lg, t, blk, psum, psq);
  } else {
#pragma unroll
    for (int n = 0; n < 8; ++n) {
      int c = n*16 + lr;
      float a = aa1[c], bo = bb1[c], bi = bias1[c];
#pragma unroll
      for (int rr = 0; rr < 4; ++rr) {
        float y = fmaxf(a*(acc1[n][rr] + bi) + bo, 0.f);
        s1[(w*16 + lg*4 + rr)*P1 + c] = f2h(y);
      }
    }
    __syncthreads();

    half8 f0 = ldv(&s1[arow*P1 +  0 + ko]);
    half8 f1 = ldv(&s1[arow*P1 + 32 + ko]);
    half8 f2 = ldv(&s1[arow*P1 + 64 + ko]);
    half8 f3 = ldv(&s1[arow*P1 + 96 + ko]);
    f32x4 acc2[8];
#pragma unroll
    for (int n = 0; n < 8; ++n) {
      const ushort_t* wrow = wb2 + (size_t)(n*16 + lr)*128 + ko;
      f32x4 c = {0.f,0.f,0.f,0.f};
      c = MF(f0, ldv(wrow +  0), c);
      c = MF(f1, ldv(wrow + 32), c);
      c = MF(f2, ldv(wrow + 64), c);
      c = MF(f3, ldv(wrow + 96), c);
      acc2[n] = c;
    }

    if constexpr (DEPTH == 2) {
      stats_and_store<8>(acc2, bias2, sred, w, lr, lg, t, blk, psum, psq);
    } else {
#pragma unroll
      for (int n = 0; n < 8; ++n) {
        int c = n*16 + lr;
        float a = aa2[c], bo = bb2[c], bi = bias2[c];
#pragma unroll
        for (int rr = 0; rr < 4; ++rr) {
          float y = fmaxf(a*(acc2[n][rr] + bi) + bo, 0.f);
          s2[(w*16 + lg*4 + rr)*P1 + c] = f2h(y);
        }
      }
      __syncthreads();

      half8 g0 = ldv(&s2[arow*P1 +  0 + ko]);
      half8 g1 = ldv(&s2[arow*P1 + 32 + ko]);
      half8 g2 = ldv(&s2[arow*P1 + 64 + ko]);
      half8 g3 = ldv(&s2[arow*P1 + 96 + ko]);
      f32x4 acc3[16];
#pragma unroll
      for (int n = 0; n < 16; ++n) {
        const ushort_t* wrow = wb3 + (size_t)(n*16 + lr)*128 + ko;
        f32x4 c = {0.f,0.f,0.f,0.f};
        c = MF(g0, ldv(wrow +  0), c);
        c = MF(g1, ldv(wrow + 32), c);
        c = MF(g2, ldv(wrow + 64), c);
        c = MF(g3, ldv(wrow + 96), c);
        acc3[n] = c;
      }

#pragma unroll
      for (int n = 0; n < 16; ++n) {
        int c = n*16 + lr;
        float bi = bias3[c];
        float x0 = acc3[n][0]+bi, x1 = acc3[n][1]+bi, x2 = acc3[n][2]+bi, x3 = acc3[n][3]+bi;
        float s4 = (x0+x1)+(x2+x3);
        float q4 = (x0*x0+x1*x1)+(x2*x2+x3*x3);
        s4 += __shfl_xor(s4, 16); s4 += __shfl_xor(s4, 32);
        q4 += __shfl_xor(q4, 16); q4 += __shfl_xor(q4, 32);
        float mx = fmaxf(fmaxf(x0,x1), fmaxf(x2,x3));
        float mn = fminf(fminf(x0,x1), fminf(x2,x3));
        mx = fmaxf(mx, __shfl_xor(mx, 16)); mx = fmaxf(mx, __shfl_xor(mx, 32));
        mn = fminf(mn, __shfl_xor(mn, 16)); mn = fminf(mn, __shfl_xor(mn, 32));
        if (lg == 0) {
          sred[w][c][0] = s4; sred[w][c][1] = q4;
          smm[w][c][0] = mx; smm[w][c][1] = mn;
        }
      }
      __syncthreads();
      if (t < 256) {
        float ps = (sred[0][t][0]+sred[1][t][0])+(sred[2][t][0]+sred[3][t][0]);
        float pq = (sred[0][t][1]+sred[1][t][1])+(sred[2][t][1]+sred[3][t][1]);
        psum[(size_t)t*NBLK + blk] = ps;
        psq [(size_t)t*NBLK + blk] = pq;
#pragma unroll
        for (int gi2 = 0; gi2 < 2; ++gi2) {
          float mx = fmaxf(smm[gi2*2][t][0], smm[gi2*2+1][t][0]);
          float mn = fminf(smm[gi2*2][t][1], smm[gi2*2+1][t][1]);
          size_t o = ((size_t)(b*256 + t))*SS + (pr*2 + gi2);
          maxb[o] = mx; minb[o] = mn;
        }
      }
    }
  }
}

// ---------- 5. finalize BN stats -> affine a,b (optional bias fold) ----------
__global__ __launch_bounds__(256) void bnstats_finalize_kernel(
    const float* __restrict__ psum, const float* __restrict__ psq,
    const float* __restrict__ gamma, const float* __restrict__ beta,
    const float* __restrict__ bias, int fold,
    float* __restrict__ aa, float* __restrict__ bb)
{
  int c = blockIdx.x, t = threadIdx.x;
  double s = 0.0, q = 0.0;
  for (int i = t; i < NBLK; i += 256) {
    s += (double)psum[(size_t)c*NBLK + i];
    q += (double)psq [(size_t)c*NBLK + i];
  }
#pragma unroll
  for (int m = 1; m <= 32; m <<= 1) { s += __shfl_xor(s, m); q += __shfl_xor(q, m); }
  __shared__ double sd[4][2];
  if ((t & 63) == 0) { sd[t>>6][0] = s; sd[t>>6][1] = q; }
  __syncthreads();
  if (t == 0) {
    double S = (sd[0][0]+sd[1][0])+(sd[2][0]+sd[3][0]);
    double Q = (sd[0][1]+sd[1][1])+(sd[2][1]+sd[3][1]);
    double mean = S / (double)MTOT;
    double var  = Q / (double)MTOT - mean*mean;
    double rs = 1.0 / sqrt(var + 1e-5);
    double a = (double)gamma[c] * rs;
    aa[c] = (float)a;
    double bbv = (double)beta[c] - mean * a;
    if (fold) bbv += a * (double)bias[c];
    bb[c] = (float)bbv;
  }
}

// ---------- 6. final output ----------
__global__ __launch_bounds__(256) void final_out_kernel(
    const float* __restrict__ aa, const float* __restrict__ bb,
    const float* __restrict__ maxb, const float* __restrict__ minb,
    float* __restrict__ out2)
{
  int blk = blockIdx.x;            // b*256 + c
  int c = blk & 255;
  float a = aa[c], bo = bb[c];
  const float* src = (a >= 0.f) ? maxb : minb;
  size_t base = (size_t)blk * SS;
  for (int s = threadIdx.x; s < SS; s += 256)
    out2[base + s] = fmaxf(fmaf(a, src[base + s], bo), 0.f);
}

// ---------- launch ----------
extern "C" void kernel_launch(void* const* d_in, const int* in_sizes, int n_in,
                              void* d_out, int out_size, void* d_ws, size_t ws_size,
                              hipStream_t stream) {
  const float* xyz    = (const float*)d_in[0];
  const float* points = (const float*)d_in[1];
  const float* W0 = (const float*)d_in[2];
  const float* b0 = (const float*)d_in[3];
  const float* g0 = (const float*)d_in[4];
  const float* be0= (const float*)d_in[5];
  const float* W1 = (const float*)d_in[6];
  const float* b1 = (const float*)d_in[7];
  const float* g1 = (const float*)d_in[8];
  const float* be1= (const float*)d_in[9];
  const float* W2 = (const float*)d_in[10];
  const float* b2 = (const float*)d_in[11];
  const float* g2 = (const float*)d_in[12];
  const float* be2= (const float*)d_in[13];

  float* out = (float*)d_out;
  float* newxyz = out;                 // (8,1024,3)
  float* out2   = out + BB*SS*3;       // (8,256,1024)

  char* ws = (char*)d_ws;
  int*      nn   = (int*)ws;
  ushort_t* wb1  = (ushort_t*)(ws + 0x100000);
  ushort_t* wb2  = (ushort_t*)(ws + 0x106000);
  ushort_t* wb3  = (ushort_t*)(ws + 0x10E000);
  float* aa1 = (float*)(ws + 0x11E000);
  float* bb1 = aa1 + 128;
  float* aa2 = bb1 + 128;
  float* bb2 = aa2 + 128;
  float* aa3 = bb2 + 128;
  float* bb3 = aa3 + 256;
  float* psum1 = (float*)(ws + 0x120000);
  float* psq1  = (float*)(ws + 0x320000);
  float* psum2 = (float*)(ws + 0x520000);
  float* psq2  = (float*)(ws + 0x720000);
  float* psum3 = (float*)(ws + 0x920000);
  float* psq3  = (float*)(ws + 0xD20000);
  float* maxb  = (float*)(ws + 0x1120000);
  float* minb  = (float*)(ws + 0x1920000);
  ushort_t* z  = (ushort_t*)(ws + 0x2120000);     // 64 MB f16 activations
  const size_t NEEDED = 0x6120000ull;

  prep_kernel<<<64, 256, 0, stream>>>(W0, W1, W2, wb1, wb2, wb3);
  fps_kernel<<<BB, 256, 0, stream>>>(xyz, newxyz);
  knn_kernel<<<BB*SS, 256, 0, stream>>>(xyz, newxyz, nn);

  if (ws_size >= NEEDED) {
    conv1_kernel<<<NBLK, 256, 0, stream>>>(xyz, points, newxyz, nn, wb1, b0,
                                           z, psum1, psq1);
    bnstats_finalize_kernel<<<O1, 256, 0, stream>>>(psum1, psq1, g0, be0, b0, 1, aa1, bb1);
    conv2_kernel<<<NBLK, 256, 0, stream>>>(z, wb2, b1, aa1, bb1, psum2, psq2);
    bnstats_finalize_kernel<<<O2, 256, 0, stream>>>(psum2, psq2, g1, be1, b1, 1, aa2, bb2);
    conv3_kernel<<<NBLK, 256, 0, stream>>>(z, wb3, b2, aa2, bb2, psum3, psq3, maxb, minb);
    bnstats_finalize_kernel<<<O3, 256, 0, stream>>>(psum3, psq3, g2, be2, b2, 0, aa3, bb3);
  } else {
    fused_kernel<1><<<NBLK, 256, 0, stream>>>(xyz, points, newxyz, nn, wb1, wb2, wb3,
        b0, b1, b2, aa1, bb1, aa2, bb2, psum1, psq1, maxb, minb);
    bnstats_finalize_kernel<<<O1, 256, 0, stream>>>(psum1, psq1, g0, be0, b0, 0, aa1, bb1);
    fused_kernel<2><<<NBLK, 256, 0, stream>>>(xyz, points, newxyz, nn, wb1, wb2, wb3,
        b0, b1, b2, aa1, bb1, aa2, bb2, psum2, psq2, maxb, minb);
    bnstats_finalize_kernel<<<O2, 256, 0, stream>>>(psum2, psq2, g1, be1, b1, 0, aa2, bb2);
    fused_kernel<3><<<NBLK, 256, 0, stream>>>(xyz, points, newxyz, nn, wb1, wb2, wb3,
        b0, b1, b2, aa1, bb1, aa2, bb2, psum3, psq3, maxb, minb);
    bnstats_finalize_kernel<<<O3, 256, 0, stream>>>(psum3, psq3, g2, be2, b2, 0, aa3, bb3);
  }

  final_out_kernel<<<BB*O3, 256, 0, stream>>>(aa3, bb3, maxb, minb, out2);
}